// Round 1
// baseline (755.932 us; speedup 1.0000x reference)
//
#include <hip/hip_runtime.h>
#include <hip/hip_bf16.h>

// ---------- complex helpers ----------
__device__ inline float2 cadd(float2 a, float2 b){ return make_float2(a.x+b.x, a.y+b.y); }
__device__ inline float2 csub(float2 a, float2 b){ return make_float2(a.x-b.x, a.y-b.y); }
__device__ inline float2 cmul(float2 a, float2 b){
    return make_float2(fmaf(a.x,b.x,-a.y*b.y), fmaf(a.x,b.y,a.y*b.x));
}

#define NPIX 60516      // 246*246
#define NFFT 288
#define NFFT2 82944     // 288*288

// ---------- twiddle table ----------
__global__ void k_tw(float2* tw) {
    int k = threadIdx.x;
    if (k < NFFT) {
        double ang = -2.0 * 3.14159265358979323846 * (double)k / (double)NFFT;
        tw[k] = make_float2((float)cos(ang), (float)sin(ang));
    }
}

// ---------- 1x1 conv 64->16 ----------
__global__ __launch_bounds__(256) void k_conv1x1_red(const float* __restrict__ x,
        const float* __restrict__ w, const float* __restrict__ bias, float* __restrict__ out) {
    __shared__ float lw[16*64];
    __shared__ float lb[16];
    for (int i = threadIdx.x; i < 1024; i += 256) lw[i] = w[i];
    if (threadIdx.x < 16) lb[threadIdx.x] = bias[threadIdx.x];
    __syncthreads();
    int idx = blockIdx.x * 256 + threadIdx.x;
    if (idx >= 8 * NPIX) return;
    int b = idx / NPIX, p = idx % NPIX;
    const float* xb = x + (size_t)b * 64 * NPIX + p;
    float acc[16];
    #pragma unroll
    for (int co = 0; co < 16; co++) acc[co] = lb[co];
    for (int ci = 0; ci < 64; ci++) {
        float v = xb[(size_t)ci * NPIX];
        #pragma unroll
        for (int co = 0; co < 16; co++) acc[co] = fmaf(lw[co*64+ci], v, acc[co]);
    }
    float* ob = out + (size_t)b * 16 * NPIX + p;
    #pragma unroll
    for (int co = 0; co < 16; co++) ob[(size_t)co*NPIX] = acc[co];
}

// ---------- 3x3 valid conv 16->16 (optional leaky) ----------
template<int HIN, bool LEAKY>
__global__ __launch_bounds__(256) void k_conv3x3(const float* __restrict__ in,
        const float* __restrict__ w, const float* __restrict__ bias, float* __restrict__ out) {
    const int HOUT = HIN - 2;
    __shared__ float lw[16*16*9];
    __shared__ float lb[16];
    for (int i = threadIdx.x; i < 2304; i += 256) lw[i] = w[i];
    if (threadIdx.x < 16) lb[threadIdx.x] = bias[threadIdx.x];
    __syncthreads();
    int idx = blockIdx.x * 256 + threadIdx.x;
    if (idx >= 8 * HOUT * HOUT) return;
    int b  = idx / (HOUT*HOUT);
    int p  = idx % (HOUT*HOUT);
    int oy = p / HOUT, ox = p % HOUT;
    float acc[16];
    #pragma unroll
    for (int co = 0; co < 16; co++) acc[co] = lb[co];
    const float* ib = in + (size_t)b * 16 * HIN * HIN;
    for (int ci = 0; ci < 16; ci++) {
        const float* ic = ib + (size_t)ci*HIN*HIN + (size_t)oy*HIN + ox;
        #pragma unroll
        for (int ky = 0; ky < 3; ky++) {
            #pragma unroll
            for (int kx = 0; kx < 3; kx++) {
                float v = ic[ky*HIN + kx];
                int base = ci*9 + ky*3 + kx;
                #pragma unroll
                for (int co = 0; co < 16; co++)
                    acc[co] = fmaf(lw[co*144 + base], v, acc[co]);
            }
        }
    }
    float* ob = out + (size_t)b*16*HOUT*HOUT + (size_t)oy*HOUT + ox;
    #pragma unroll
    for (int co = 0; co < 16; co++) {
        float r = acc[co];
        if (LEAKY) r = (r >= 0.f) ? r : 0.1f*r;
        ob[(size_t)co*HOUT*HOUT] = r;
    }
}

// ---------- adaptive pool (240,240)->(3,3) ----------
__global__ __launch_bounds__(256) void k_pool3(const float* __restrict__ in, float* __restrict__ out) {
    int bc = blockIdx.x;           // (b*16+c)*9 + cell
    int cell = bc % 9, ch = bc / 9;
    int by = cell / 3, bx = cell % 3;
    const float* base = in + (size_t)ch * 240*240 + (size_t)by*80*240 + bx*80;
    float s = 0.f;
    for (int i = threadIdx.x; i < 6400; i += 256) {
        int r = i / 80, c = i % 80;
        s += base[r*240 + c];
    }
    __shared__ float red[256];
    red[threadIdx.x] = s; __syncthreads();
    for (int st = 128; st > 0; st >>= 1) {
        if (threadIdx.x < st) red[threadIdx.x] += red[threadIdx.x+st];
        __syncthreads();
    }
    if (threadIdx.x == 0) out[bc] = red[0] * (1.f/6400.f);
}

// ---------- kernel_P: 1x1 conv (16->16) + exp + spatial-mean subtraction ----------
__global__ void k_kernelP(const float* __restrict__ pooled, const float* __restrict__ w,
                          const float* __restrict__ bias, float* __restrict__ out) {
    int b = blockIdx.x / 16, co = blockIdx.x % 16;
    __shared__ float vals[9];
    int t = threadIdx.x;
    if (t < 9) {
        float a = bias[co];
        for (int ci = 0; ci < 16; ci++) a += pooled[(b*16+ci)*9 + t] * w[co*16+ci];
        vals[t] = expf(a);
    }
    __syncthreads();
    if (t < 9) {
        float m = 0.f;
        #pragma unroll
        for (int i = 0; i < 9; i++) m += vals[i];
        m *= (1.f/9.f);
        out[(b*16+co)*9 + t] = vals[t] - m;
    }
}

// ---------- psf builders (circularly shifted kernels) ----------
__global__ __launch_bounds__(256) void k_psfK(const float* __restrict__ ker, float2* __restrict__ Kf) {
    int idx = blockIdx.x*256 + threadIdx.x;
    if (idx >= 8*NFFT2) return;
    int pos = idx % NFFT2, b = idx / NFFT2;
    int y = pos / NFFT, x = pos % NFFT;
    int ry = (y < 11) ? y+10 : ((y >= 278) ? y-278 : -1);
    int rx = (x < 11) ? x+10 : ((x >= 278) ? x-278 : -1);
    float v = (ry >= 0 && rx >= 0) ? ker[b*441 + ry*21 + rx] : 0.f;
    Kf[idx] = make_float2(v, 0.f);
}

__global__ __launch_bounds__(256) void k_psfP(const float* __restrict__ kP, float2* __restrict__ Pf) {
    int idx = blockIdx.x*256 + threadIdx.x;
    if (idx >= 128*NFFT2) return;
    int pos = idx % NFFT2, ch = idx / NFFT2;
    int y = pos / NFFT, x = pos % NFFT;
    int ry = (y < 2) ? y+1 : ((y == 287) ? 0 : -1);
    int rx = (x < 2) ? x+1 : ((x == 287) ? 0 : -1);
    float v = (ry >= 0 && rx >= 0) ? kP[ch*9 + ry*3 + rx] : 0.f;
    Pf[idx] = make_float2(v, 0.f);
}

// ---------- edge-pad cls -> complex ----------
__global__ __launch_bounds__(256) void k_build_fp(const float* __restrict__ cls, float2* __restrict__ Z) {
    int idx = blockIdx.x*256 + threadIdx.x;
    if (idx >= 128*NFFT2) return;
    int pos = idx % NFFT2, ch = idx / NFFT2;
    int y = pos / NFFT, x = pos % NFFT;
    int iy = min(max(y-21, 0), 245), ix = min(max(x-21, 0), 245);
    float v = cls[(size_t)ch*NPIX + iy*246 + ix];
    Z[idx] = make_float2(v, 0.f);
}

// ---------- mixed-radix Stockham FFT-288 over rows (one wave per row) ----------
template<bool INV>
__global__ __launch_bounds__(256) void k_fft_rows(const float2* __restrict__ src,
        float2* __restrict__ dst, const float2* __restrict__ tw) {
    __shared__ float2 A[4][NFFT];
    __shared__ float2 B[4][NFFT];
    int t = threadIdx.x, w = t >> 6, lane = t & 63;
    size_t row = (size_t)blockIdx.x*4 + w;
    const float2* s = src + row*NFFT;

    float2* X = A[w];
    float2* Y = B[w];
    for (int j = lane; j < NFFT; j += 64) X[j] = s[j];
    __syncthreads();

    auto TW = [&](int k) { float2 v = tw[k]; if (INV) v.y = -v.y; return v; };

    // stage 1: r=4, n=288, m=72, s=1
    for (int it = lane; it < 72; it += 64) {
        int p = it;
        float2 a0=X[p], a1=X[p+72], a2=X[p+144], a3=X[p+216];
        float2 t0=cadd(a0,a2), t1=csub(a0,a2), t2=cadd(a1,a3), t3=csub(a1,a3);
        float2 b0=cadd(t0,t2), b2=csub(t0,t2);
        float2 b1, b3;
        if (!INV) { b1=make_float2(t1.x+t3.y, t1.y-t3.x); b3=make_float2(t1.x-t3.y, t1.y+t3.x); }
        else      { b1=make_float2(t1.x-t3.y, t1.y+t3.x); b3=make_float2(t1.x+t3.y, t1.y-t3.x); }
        Y[4*p+0]=b0; Y[4*p+1]=cmul(b1,TW(p)); Y[4*p+2]=cmul(b2,TW(2*p)); Y[4*p+3]=cmul(b3,TW(3*p));
    }
    __syncthreads();
    { float2* tmp=X; X=Y; Y=tmp; }
    // stage 2: r=4, n=72, m=18, s=4
    for (int it = lane; it < 72; it += 64) {
        int p = it >> 2, q = it & 3;
        int i0 = q + 4*p;
        float2 a0=X[i0], a1=X[i0+72], a2=X[i0+144], a3=X[i0+216];
        float2 t0=cadd(a0,a2), t1=csub(a0,a2), t2=cadd(a1,a3), t3=csub(a1,a3);
        float2 b0=cadd(t0,t2), b2=csub(t0,t2);
        float2 b1, b3;
        if (!INV) { b1=make_float2(t1.x+t3.y, t1.y-t3.x); b3=make_float2(t1.x-t3.y, t1.y+t3.x); }
        else      { b1=make_float2(t1.x-t3.y, t1.y+t3.x); b3=make_float2(t1.x+t3.y, t1.y-t3.x); }
        int o = q + 16*p;
        Y[o]=b0; Y[o+4]=cmul(b1,TW(4*p)); Y[o+8]=cmul(b2,TW(8*p)); Y[o+12]=cmul(b3,TW(12*p));
    }
    __syncthreads();
    { float2* tmp=X; X=Y; Y=tmp; }
    // stage 3: r=2, n=18, m=9, s=16
    for (int it = lane; it < 144; it += 64) {
        int p = it >> 4, q = it & 15;
        int i0 = q + 16*p;
        float2 a0=X[i0], a1=X[i0+144];
        float2 b0=cadd(a0,a1), b1=csub(a0,a1);
        int o = q + 32*p;
        Y[o]=b0; Y[o+16]=cmul(b1,TW(16*p));
    }
    __syncthreads();
    { float2* tmp=X; X=Y; Y=tmp; }
    // stage 4: r=3, n=9, m=3, s=32
    {
        const float d = INV ? 0.8660254037844386f : -0.8660254037844386f;
        for (int it = lane; it < 96; it += 64) {
            int p = it >> 5, q = it & 31;
            int i0 = q + 32*p;
            float2 a0=X[i0], a1=X[i0+96], a2=X[i0+192];
            float2 tt=cadd(a1,a2), u=csub(a1,a2);
            float2 b0=cadd(a0,tt);
            float2 b1=make_float2(a0.x-0.5f*tt.x - d*u.y, a0.y-0.5f*tt.y + d*u.x);
            float2 b2=make_float2(a0.x-0.5f*tt.x + d*u.y, a0.y-0.5f*tt.y - d*u.x);
            int o = q + 96*p;
            Y[o]=b0; Y[o+32]=cmul(b1,TW(32*p)); Y[o+64]=cmul(b2,TW(64*p));
        }
    }
    __syncthreads();
    { float2* tmp=X; X=Y; Y=tmp; }
    // stage 5: r=3, n=3, m=1, s=96 (no twiddles)
    {
        const float d = INV ? 0.8660254037844386f : -0.8660254037844386f;
        for (int it = lane; it < 96; it += 64) {
            int q = it;
            float2 a0=X[q], a1=X[q+96], a2=X[q+192];
            float2 tt=cadd(a1,a2), u=csub(a1,a2);
            float2 b0=cadd(a0,tt);
            float2 b1=make_float2(a0.x-0.5f*tt.x - d*u.y, a0.y-0.5f*tt.y + d*u.x);
            float2 b2=make_float2(a0.x-0.5f*tt.x + d*u.y, a0.y-0.5f*tt.y - d*u.x);
            Y[q]=b0; Y[q+96]=b1; Y[q+192]=b2;
        }
    }
    __syncthreads();
    { float2* tmp=X; X=Y; Y=tmp; }

    float2* dout = dst + row*NFFT;
    for (int j = lane; j < NFFT; j += 64) dout[j] = X[j];
}

// ---------- in-place batched 288x288 transpose (tile pairs) ----------
__global__ __launch_bounds__(256) void k_transpose(float2* __restrict__ M) {
    int pair = blockIdx.x % 45;
    int ch   = blockIdx.x / 45;
    int ti = 0, rem = pair;
    while (rem >= 9 - ti) { rem -= 9 - ti; ti++; }
    int tj = ti + rem;
    float2* base = M + (size_t)ch * NFFT2;
    __shared__ float2 TA[32][33];
    __shared__ float2 TB[32][33];
    int tx = threadIdx.x & 31, ty0 = threadIdx.x >> 5;
    #pragma unroll
    for (int k = 0; k < 4; k++) {
        int ty = ty0 + k*8;
        TA[ty][tx] = base[(size_t)(ti*32+ty)*NFFT + tj*32 + tx];
        if (ti != tj) TB[ty][tx] = base[(size_t)(tj*32+ty)*NFFT + ti*32 + tx];
    }
    __syncthreads();
    #pragma unroll
    for (int k = 0; k < 4; k++) {
        int ty = ty0 + k*8;
        base[(size_t)(tj*32+ty)*NFFT + ti*32 + tx] = TA[tx][ty];
        if (ti != tj) base[(size_t)(ti*32+ty)*NFFT + tj*32 + tx] = TB[tx][ty];
    }
}

// ---------- pointwise: Z *= conj(Kf) / (|Kf|^2 + |Pf|^2) ----------
__global__ __launch_bounds__(256) void k_invker(float2* __restrict__ Z,
        const float2* __restrict__ Kf, const float2* __restrict__ Pf) {
    int idx = blockIdx.x*256 + threadIdx.x;
    if (idx >= 128*NFFT2) return;
    int pos = idx % NFFT2, ch = idx / NFFT2, b = ch >> 4;
    float2 z = Z[idx];
    float2 k = Kf[(size_t)b*NFFT2 + pos];
    float2 p = Pf[idx];
    float denom = k.x*k.x + k.y*k.y + p.x*p.x + p.y*p.y;
    float inv = 1.0f / denom;
    float2 ik = make_float2(k.x*inv, -k.y*inv);
    Z[idx] = cmul(ik, z);
}

// ---------- crop real part, scale by 1/N^2 ----------
__global__ __launch_bounds__(256) void k_crop(const float2* __restrict__ Z, float* __restrict__ clear) {
    int idx = blockIdx.x*256 + threadIdx.x;
    if (idx >= 128*NPIX) return;
    int pos = idx % NPIX, ch = idx / NPIX;
    int y = pos / 246, x = pos % 246;
    clear[idx] = Z[(size_t)ch*NFFT2 + (size_t)(y+21)*NFFT + (x+21)].x * (1.0f/82944.0f);
}

// ---------- 1x1 conv 16->64 ----------
__global__ __launch_bounds__(256) void k_conv1x1_exp(const float* __restrict__ clear,
        const float* __restrict__ w, const float* __restrict__ bias, float* __restrict__ out) {
    __shared__ float lw[64*16];
    __shared__ float lb[64];
    for (int i = threadIdx.x; i < 1024; i += 256) lw[i] = w[i];
    if (threadIdx.x < 64) lb[threadIdx.x] = bias[threadIdx.x];
    __syncthreads();
    int idx = blockIdx.x * 256 + threadIdx.x;
    if (idx >= 8 * NPIX) return;
    int b = idx / NPIX, p = idx % NPIX;
    const float* cb = clear + (size_t)b * 16 * NPIX + p;
    float v[16];
    #pragma unroll
    for (int ci = 0; ci < 16; ci++) v[ci] = cb[(size_t)ci*NPIX];
    float* ob = out + (size_t)b * 64 * NPIX + p;
    #pragma unroll
    for (int co = 0; co < 64; co++) {
        float a = lb[co];
        #pragma unroll
        for (int ci = 0; ci < 16; ci++) a = fmaf(lw[co*16+ci], v[ci], a);
        ob[(size_t)co*NPIX] = a;
    }
}

extern "C" void kernel_launch(void* const* d_in, const int* in_sizes, int n_in,
                              void* d_out, int out_size, void* d_ws, size_t ws_size,
                              hipStream_t stream) {
    const float* x     = (const float*)d_in[0];
    const float* ker   = (const float*)d_in[1];
    const float* w_red = (const float*)d_in[2];
    const float* b_red = (const float*)d_in[3];
    const float* w_g1  = (const float*)d_in[4];
    const float* b_g1  = (const float*)d_in[5];
    const float* w_g2  = (const float*)d_in[6];
    const float* b_g2  = (const float*)d_in[7];
    const float* w_g3  = (const float*)d_in[8];
    const float* b_g3  = (const float*)d_in[9];
    const float* w_g4  = (const float*)d_in[10];
    const float* b_g4  = (const float*)d_in[11];
    const float* w_exp = (const float*)d_in[12];
    const float* b_exp = (const float*)d_in[13];
    float* out = (float*)d_out;

    char* ws = (char*)d_ws;
    size_t off = 0;
    auto alloc = [&](size_t bytes) -> char* {
        char* p = ws + off; off += (bytes + 255) & ~(size_t)255; return p;
    };
    float*  cls    = (float*) alloc(7746048ull * 4);           // (8,16,246,246)
    float*  pooled = (float*) alloc(1152 * 4);                 // (8,16,3,3)
    float*  kP     = (float*) alloc(1152 * 4);                 // (8,16,3,3)
    float2* tw     = (float2*)alloc(288 * 8);
    float2* Kf     = (float2*)alloc(663552ull * 8);            // (8,288,288) complex
    float2* Zb     = (float2*)alloc(10616832ull * 8);          // (8,16,288,288) complex
    float2* Pf     = (float2*)alloc(10616832ull * 8);          // (8,16,288,288) complex
    // h-chain buffers alias the Zb region (Zb first used after pooling is done)
    float*  ha     = (float*)Zb;                               // up to (8,16,244,244)
    float*  hb     = ha + 7620608ull;                          // up to (8,16,242,242)

    k_tw<<<1, 320, 0, stream>>>(tw);
    k_conv1x1_red<<<1892, 256, 0, stream>>>(x, w_red, b_red, cls);
    k_conv3x3<246, true ><<<1861, 256, 0, stream>>>(cls, w_g1, b_g1, ha);
    k_conv3x3<244, true ><<<1831, 256, 0, stream>>>(ha,  w_g2, b_g2, hb);
    k_conv3x3<242, false><<<1800, 256, 0, stream>>>(hb,  w_g3, b_g3, ha);
    k_pool3<<<1152, 256, 0, stream>>>(ha, pooled);
    k_kernelP<<<128, 64, 0, stream>>>(pooled, w_g4, b_g4, kP);

    // Pf = fft2(psf(kernel_P))   (ends in transposed layout — consistent everywhere)
    k_psfP<<<41472, 256, 0, stream>>>(kP, Pf);
    k_fft_rows<false><<<9216, 256, 0, stream>>>(Pf, Pf, tw);
    k_transpose<<<128*45, 256, 0, stream>>>(Pf);
    k_fft_rows<false><<<9216, 256, 0, stream>>>(Pf, Pf, tw);

    // Kf = fft2(psf(kernel))
    k_psfK<<<2592, 256, 0, stream>>>(ker, Kf);
    k_fft_rows<false><<<576, 256, 0, stream>>>(Kf, Kf, tw);
    k_transpose<<<8*45, 256, 0, stream>>>(Kf);
    k_fft_rows<false><<<576, 256, 0, stream>>>(Kf, Kf, tw);

    // Xf = fft2(edge-pad(cls))
    k_build_fp<<<41472, 256, 0, stream>>>(cls, Zb);
    k_fft_rows<false><<<9216, 256, 0, stream>>>(Zb, Zb, tw);
    k_transpose<<<128*45, 256, 0, stream>>>(Zb);
    k_fft_rows<false><<<9216, 256, 0, stream>>>(Zb, Zb, tw);

    // Z = conj(Kf)/(|Kf|^2+|Pf|^2) * Xf
    k_invker<<<41472, 256, 0, stream>>>(Zb, Kf, Pf);

    // deblur = ifft2(Z)
    k_fft_rows<true><<<9216, 256, 0, stream>>>(Zb, Zb, tw);
    k_transpose<<<128*45, 256, 0, stream>>>(Zb);
    k_fft_rows<true><<<9216, 256, 0, stream>>>(Zb, Zb, tw);

    // clear = crop(real(deblur))/N^2  (reuse cls buffer)
    k_crop<<<30258, 256, 0, stream>>>(Zb, cls);

    // out = conv1x1 16->64
    k_conv1x1_exp<<<1892, 256, 0, stream>>>(cls, w_exp, b_exp, out);
}

// Round 2
// 472.218 us; speedup vs baseline: 1.6008x; 1.6008x over previous
//
#include <hip/hip_runtime.h>
#include <hip/hip_bf16.h>

// ---------- complex helpers ----------
__device__ inline float2 cadd(float2 a, float2 b){ return make_float2(a.x+b.x, a.y+b.y); }
__device__ inline float2 csub(float2 a, float2 b){ return make_float2(a.x-b.x, a.y-b.y); }
__device__ inline float2 cmul(float2 a, float2 b){
    return make_float2(fmaf(a.x,b.x,-a.y*b.y), fmaf(a.x,b.y,a.y*b.x));
}

#define NPIX 60516      // 246*246
#define NFFT 288
#define NFFT2 82944     // 288*288

// ---------- twiddle table ----------
__global__ void k_tw(float2* tw) {
    int k = threadIdx.x;
    if (k < NFFT) {
        double ang = -2.0 * 3.14159265358979323846 * (double)k / (double)NFFT;
        tw[k] = make_float2((float)cos(ang), (float)sin(ang));
    }
}

// ---------- 1x1 conv 64->16 (weights scalarized from global) ----------
__global__ __launch_bounds__(256) void k_conv1x1_red(const float* __restrict__ x,
        const float* __restrict__ w, const float* __restrict__ bias, float* __restrict__ out) {
    int idx = blockIdx.x * 256 + threadIdx.x;
    if (idx >= 8 * NPIX) return;
    int b = idx / NPIX, p = idx % NPIX;
    const float* xb = x + (size_t)b * 64 * NPIX + p;
    float acc[16];
    #pragma unroll
    for (int co = 0; co < 16; co++) acc[co] = bias[co];
    for (int ci = 0; ci < 64; ci++) {
        float v = xb[(size_t)ci * NPIX];
        #pragma unroll
        for (int co = 0; co < 16; co++) acc[co] = fmaf(w[co*64+ci], v, acc[co]);
    }
    float* ob = out + (size_t)b * 16 * NPIX + p;
    #pragma unroll
    for (int co = 0; co < 16; co++) ob[(size_t)co*NPIX] = acc[co];
}

// ---------- 3x3 valid conv 16->16, 4 px/thread, scalar weights ----------
template<int HIN, bool LEAKY>
__global__ __launch_bounds__(256) void k_conv3x3(const float* __restrict__ in,
        const float* __restrict__ w, const float* __restrict__ bias, float* __restrict__ out) {
    const int HOUT = HIN - 2;
    const int GX = (HOUT + 3) / 4;
    int idx = blockIdx.x * 256 + threadIdx.x;
    if (idx >= 8 * HOUT * GX) return;
    int b  = idx / (HOUT * GX);
    int r  = idx % (HOUT * GX);
    int oy = r / GX;
    int ox0 = (r % GX) * 4;

    float acc[16][4];
    #pragma unroll
    for (int co = 0; co < 16; co++) {
        float bb = bias[co];
        #pragma unroll
        for (int px = 0; px < 4; px++) acc[co][px] = bb;
    }

    const float* ib = in + (size_t)b * 16 * HIN * HIN + (size_t)oy * HIN;
    for (int ci = 0; ci < 16; ci++) {
        const float* ic = ib + (size_t)ci * HIN * HIN;
        #pragma unroll
        for (int ky = 0; ky < 3; ky++) {
            float in6[6];
            #pragma unroll
            for (int j = 0; j < 6; j++) {
                int xx = ox0 + j;
                if (HOUT % 4 != 0) { if (xx > HIN - 1) xx = HIN - 1; }
                in6[j] = ic[ky * HIN + xx];
            }
            #pragma unroll
            for (int kx = 0; kx < 3; kx++) {
                #pragma unroll
                for (int co = 0; co < 16; co++) {
                    float wv = w[co*144 + ci*9 + ky*3 + kx];   // uniform -> SGPR
                    #pragma unroll
                    for (int px = 0; px < 4; px++)
                        acc[co][px] = fmaf(wv, in6[px + kx], acc[co][px]);
                }
            }
        }
    }

    float* ob = out + (size_t)b * 16 * HOUT * HOUT + (size_t)oy * HOUT + ox0;
    #pragma unroll
    for (int co = 0; co < 16; co++) {
        #pragma unroll
        for (int px = 0; px < 4; px++) {
            if (HOUT % 4 == 0 || ox0 + px < HOUT) {
                float v = acc[co][px];
                if (LEAKY) v = (v >= 0.f) ? v : 0.1f * v;
                ob[(size_t)co * HOUT * HOUT + px] = v;
            }
        }
    }
}

// ---------- adaptive pool (240,240)->(3,3) ----------
__global__ __launch_bounds__(256) void k_pool3(const float* __restrict__ in, float* __restrict__ out) {
    int bc = blockIdx.x;
    int cell = bc % 9, ch = bc / 9;
    int by = cell / 3, bx = cell % 3;
    const float* base = in + (size_t)ch * 240*240 + (size_t)by*80*240 + bx*80;
    float s = 0.f;
    for (int i = threadIdx.x; i < 6400; i += 256) {
        int r = i / 80, c = i % 80;
        s += base[r*240 + c];
    }
    __shared__ float red[256];
    red[threadIdx.x] = s; __syncthreads();
    for (int st = 128; st > 0; st >>= 1) {
        if (threadIdx.x < st) red[threadIdx.x] += red[threadIdx.x+st];
        __syncthreads();
    }
    if (threadIdx.x == 0) out[bc] = red[0] * (1.f/6400.f);
}

// ---------- kernel_P: 1x1 conv (16->16) + exp + spatial-mean subtraction ----------
__global__ void k_kernelP(const float* __restrict__ pooled, const float* __restrict__ w,
                          const float* __restrict__ bias, float* __restrict__ out) {
    int b = blockIdx.x / 16, co = blockIdx.x % 16;
    __shared__ float vals[9];
    int t = threadIdx.x;
    if (t < 9) {
        float a = bias[co];
        for (int ci = 0; ci < 16; ci++) a += pooled[(b*16+ci)*9 + t] * w[co*16+ci];
        vals[t] = expf(a);
    }
    __syncthreads();
    if (t < 9) {
        float m = 0.f;
        #pragma unroll
        for (int i = 0; i < 9; i++) m += vals[i];
        m *= (1.f/9.f);
        out[(b*16+co)*9 + t] = vals[t] - m;
    }
}

// ---------- psf builder for K (8 batch kernels, unpacked) ----------
__global__ __launch_bounds__(256) void k_psfK(const float* __restrict__ ker, float2* __restrict__ Kf) {
    int idx = blockIdx.x*256 + threadIdx.x;
    if (idx >= 8*NFFT2) return;
    int pos = idx % NFFT2, b = idx / NFFT2;
    int y = pos / NFFT, x = pos % NFFT;
    int ry = (y < 11) ? y+10 : ((y >= 278) ? y-278 : -1);
    int rx = (x < 11) ? x+10 : ((x >= 278) ? x-278 : -1);
    float v = (ry >= 0 && rx >= 0) ? ker[b*441 + ry*21 + rx] : 0.f;
    Kf[idx] = make_float2(v, 0.f);
}

// ---------- psf builder for P, PACKED: z = psf(ch 2pc) + i psf(ch 2pc+1) ----------
__global__ __launch_bounds__(256) void k_psfP(const float* __restrict__ kP, float2* __restrict__ PZ) {
    int idx = blockIdx.x*256 + threadIdx.x;
    if (idx >= 64*NFFT2) return;
    int pos = idx % NFFT2, pc = idx / NFFT2;
    int y = pos / NFFT, x = pos % NFFT;
    int ry = (y < 2) ? y+1 : ((y == 287) ? 0 : -1);
    int rx = (x < 2) ? x+1 : ((x == 287) ? 0 : -1);
    float v0 = 0.f, v1 = 0.f;
    if (ry >= 0 && rx >= 0) {
        v0 = kP[(2*pc)  *9 + ry*3 + rx];
        v1 = kP[(2*pc+1)*9 + ry*3 + rx];
    }
    PZ[idx] = make_float2(v0, v1);
}

// ---------- edge-pad cls -> PACKED complex (ch 2pc real, 2pc+1 imag) ----------
__global__ __launch_bounds__(256) void k_build_fp(const float* __restrict__ cls, float2* __restrict__ Z) {
    int idx = blockIdx.x*256 + threadIdx.x;
    if (idx >= 64*NFFT2) return;
    int pos = idx % NFFT2, pc = idx / NFFT2;
    int y = pos / NFFT, x = pos % NFFT;
    int iy = min(max(y-21, 0), 245), ix = min(max(x-21, 0), 245);
    const float* c0 = cls + (size_t)(2*pc) * NPIX + iy*246 + ix;
    Z[idx] = make_float2(c0[0], c0[NPIX]);
}

// ---------- mixed-radix Stockham FFT-288 over rows (one wave per row) ----------
template<bool INV>
__global__ __launch_bounds__(256) void k_fft_rows(const float2* __restrict__ src,
        float2* __restrict__ dst, const float2* __restrict__ tw) {
    __shared__ float2 A[4][NFFT];
    __shared__ float2 B[4][NFFT];
    int t = threadIdx.x, w = t >> 6, lane = t & 63;
    size_t row = (size_t)blockIdx.x*4 + w;
    const float2* s = src + row*NFFT;

    float2* X = A[w];
    float2* Y = B[w];
    for (int j = lane; j < NFFT; j += 64) X[j] = s[j];
    __syncthreads();

    auto TW = [&](int k) { float2 v = tw[k]; if (INV) v.y = -v.y; return v; };

    // stage 1: r=4, n=288, m=72, s=1
    for (int it = lane; it < 72; it += 64) {
        int p = it;
        float2 a0=X[p], a1=X[p+72], a2=X[p+144], a3=X[p+216];
        float2 t0=cadd(a0,a2), t1=csub(a0,a2), t2=cadd(a1,a3), t3=csub(a1,a3);
        float2 b0=cadd(t0,t2), b2=csub(t0,t2);
        float2 b1, b3;
        if (!INV) { b1=make_float2(t1.x+t3.y, t1.y-t3.x); b3=make_float2(t1.x-t3.y, t1.y+t3.x); }
        else      { b1=make_float2(t1.x-t3.y, t1.y+t3.x); b3=make_float2(t1.x+t3.y, t1.y-t3.x); }
        Y[4*p+0]=b0; Y[4*p+1]=cmul(b1,TW(p)); Y[4*p+2]=cmul(b2,TW(2*p)); Y[4*p+3]=cmul(b3,TW(3*p));
    }
    __syncthreads();
    { float2* tmp=X; X=Y; Y=tmp; }
    // stage 2: r=4, n=72, m=18, s=4
    for (int it = lane; it < 72; it += 64) {
        int p = it >> 2, q = it & 3;
        int i0 = q + 4*p;
        float2 a0=X[i0], a1=X[i0+72], a2=X[i0+144], a3=X[i0+216];
        float2 t0=cadd(a0,a2), t1=csub(a0,a2), t2=cadd(a1,a3), t3=csub(a1,a3);
        float2 b0=cadd(t0,t2), b2=csub(t0,t2);
        float2 b1, b3;
        if (!INV) { b1=make_float2(t1.x+t3.y, t1.y-t3.x); b3=make_float2(t1.x-t3.y, t1.y+t3.x); }
        else      { b1=make_float2(t1.x-t3.y, t1.y+t3.x); b3=make_float2(t1.x+t3.y, t1.y-t3.x); }
        int o = q + 16*p;
        Y[o]=b0; Y[o+4]=cmul(b1,TW(4*p)); Y[o+8]=cmul(b2,TW(8*p)); Y[o+12]=cmul(b3,TW(12*p));
    }
    __syncthreads();
    { float2* tmp=X; X=Y; Y=tmp; }
    // stage 3: r=2, n=18, m=9, s=16
    for (int it = lane; it < 144; it += 64) {
        int p = it >> 4, q = it & 15;
        int i0 = q + 16*p;
        float2 a0=X[i0], a1=X[i0+144];
        float2 b0=cadd(a0,a1), b1=csub(a0,a1);
        int o = q + 32*p;
        Y[o]=b0; Y[o+16]=cmul(b1,TW(16*p));
    }
    __syncthreads();
    { float2* tmp=X; X=Y; Y=tmp; }
    // stage 4: r=3, n=9, m=3, s=32
    {
        const float d = INV ? 0.8660254037844386f : -0.8660254037844386f;
        for (int it = lane; it < 96; it += 64) {
            int p = it >> 5, q = it & 31;
            int i0 = q + 32*p;
            float2 a0=X[i0], a1=X[i0+96], a2=X[i0+192];
            float2 tt=cadd(a1,a2), u=csub(a1,a2);
            float2 b0=cadd(a0,tt);
            float2 b1=make_float2(a0.x-0.5f*tt.x - d*u.y, a0.y-0.5f*tt.y + d*u.x);
            float2 b2=make_float2(a0.x-0.5f*tt.x + d*u.y, a0.y-0.5f*tt.y - d*u.x);
            int o = q + 96*p;
            Y[o]=b0; Y[o+32]=cmul(b1,TW(32*p)); Y[o+64]=cmul(b2,TW(64*p));
        }
    }
    __syncthreads();
    { float2* tmp=X; X=Y; Y=tmp; }
    // stage 5: r=3, n=3, m=1, s=96 (no twiddles)
    {
        const float d = INV ? 0.8660254037844386f : -0.8660254037844386f;
        for (int it = lane; it < 96; it += 64) {
            int q = it;
            float2 a0=X[q], a1=X[q+96], a2=X[q+192];
            float2 tt=cadd(a1,a2), u=csub(a1,a2);
            float2 b0=cadd(a0,tt);
            float2 b1=make_float2(a0.x-0.5f*tt.x - d*u.y, a0.y-0.5f*tt.y + d*u.x);
            float2 b2=make_float2(a0.x-0.5f*tt.x + d*u.y, a0.y-0.5f*tt.y - d*u.x);
            Y[q]=b0; Y[q+96]=b1; Y[q+192]=b2;
        }
    }
    __syncthreads();
    { float2* tmp=X; X=Y; Y=tmp; }

    float2* dout = dst + row*NFFT;
    for (int j = lane; j < NFFT; j += 64) dout[j] = X[j];
}

// ---------- in-place batched 288x288 transpose (tile pairs) ----------
__global__ __launch_bounds__(256) void k_transpose(float2* __restrict__ M) {
    int pair = blockIdx.x % 45;
    int ch   = blockIdx.x / 45;
    int ti = 0, rem = pair;
    while (rem >= 9 - ti) { rem -= 9 - ti; ti++; }
    int tj = ti + rem;
    float2* base = M + (size_t)ch * NFFT2;
    __shared__ float2 TA[32][33];
    __shared__ float2 TB[32][33];
    int tx = threadIdx.x & 31, ty0 = threadIdx.x >> 5;
    #pragma unroll
    for (int k = 0; k < 4; k++) {
        int ty = ty0 + k*8;
        TA[ty][tx] = base[(size_t)(ti*32+ty)*NFFT + tj*32 + tx];
        if (ti != tj) TB[ty][tx] = base[(size_t)(tj*32+ty)*NFFT + ti*32 + tx];
    }
    __syncthreads();
    #pragma unroll
    for (int k = 0; k < 4; k++) {
        int ty = ty0 + k*8;
        base[(size_t)(tj*32+ty)*NFFT + ti*32 + tx] = TA[tx][ty];
        if (ti != tj) base[(size_t)(ti*32+ty)*NFFT + tj*32 + tx] = TB[tx][ty];
    }
}

// ---------- packed Wiener filter: unpack via conj-symmetry, filter, repack ----------
__global__ __launch_bounds__(256) void k_invker_packed(const float2* __restrict__ Z,
        const float2* __restrict__ PZ, const float2* __restrict__ Kf, float2* __restrict__ Zo) {
    int idx = blockIdx.x*256 + threadIdx.x;
    if (idx >= 64*NFFT2) return;
    int pos = idx % NFFT2, pc = idx / NFFT2, b = pc >> 3;
    int y = pos / NFFT, x = pos % NFFT;
    int my = (y == 0) ? 0 : NFFT - y;
    int mx = (x == 0) ? 0 : NFFT - x;
    int mpos = my*NFFT + mx;
    size_t base = (size_t)pc * NFFT2;
    float2 zk = Z[base + pos],  zm = Z[base + mpos];
    float2 pk = PZ[base + pos], pm = PZ[base + mpos];
    float2 K  = Kf[(size_t)b * NFFT2 + pos];
    // unpack spectra of the two real channels
    float2 A  = make_float2(0.5f*(zk.x + zm.x), 0.5f*(zk.y - zm.y));
    float2 Bv = make_float2(0.5f*(zk.y + zm.y), -0.5f*(zk.x - zm.x));
    float2 Pa = make_float2(0.5f*(pk.x + pm.x), 0.5f*(pk.y - pm.y));
    float2 Pb = make_float2(0.5f*(pk.y + pm.y), -0.5f*(pk.x - pm.x));
    float kk = K.x*K.x + K.y*K.y;
    float ra = 1.0f / (kk + Pa.x*Pa.x + Pa.y*Pa.y);
    float rb = 1.0f / (kk + Pb.x*Pb.x + Pb.y*Pb.y);
    float2 Ha = make_float2(K.x*ra, -K.y*ra);
    float2 Hb = make_float2(K.x*rb, -K.y*rb);
    float2 Fa = cmul(Ha, A);
    float2 Fb = cmul(Hb, Bv);
    Zo[idx] = make_float2(Fa.x - Fb.y, Fa.y + Fb.x);   // Fa + i*Fb
}

// ---------- fused crop + 1x1 conv 16->64 (reads packed spatial result) ----------
__global__ __launch_bounds__(256) void k_conv1x1_exp(const float2* __restrict__ Zc,
        const float* __restrict__ w, const float* __restrict__ bias, float* __restrict__ out) {
    int idx = blockIdx.x * 256 + threadIdx.x;
    if (idx >= 8 * NPIX) return;
    int b = idx / NPIX, p = idx % NPIX;
    int y = p / 246, x = p % 246;
    size_t zoff = (size_t)(y + 21) * NFFT + (x + 21);
    const float s = 1.0f / 82944.0f;
    float v[16];
    #pragma unroll
    for (int h = 0; h < 8; h++) {
        float2 z = Zc[(size_t)(b*8 + h) * NFFT2 + zoff];
        v[2*h]   = z.x * s;
        v[2*h+1] = z.y * s;
    }
    float* ob = out + (size_t)b * 64 * NPIX + p;
    #pragma unroll
    for (int co = 0; co < 64; co++) {
        float a = bias[co];
        #pragma unroll
        for (int ci = 0; ci < 16; ci++) a = fmaf(w[co*16+ci], v[ci], a);
        ob[(size_t)co*NPIX] = a;
    }
}

extern "C" void kernel_launch(void* const* d_in, const int* in_sizes, int n_in,
                              void* d_out, int out_size, void* d_ws, size_t ws_size,
                              hipStream_t stream) {
    const float* x     = (const float*)d_in[0];
    const float* ker   = (const float*)d_in[1];
    const float* w_red = (const float*)d_in[2];
    const float* b_red = (const float*)d_in[3];
    const float* w_g1  = (const float*)d_in[4];
    const float* b_g1  = (const float*)d_in[5];
    const float* w_g2  = (const float*)d_in[6];
    const float* b_g2  = (const float*)d_in[7];
    const float* w_g3  = (const float*)d_in[8];
    const float* b_g3  = (const float*)d_in[9];
    const float* w_g4  = (const float*)d_in[10];
    const float* b_g4  = (const float*)d_in[11];
    const float* w_exp = (const float*)d_in[12];
    const float* b_exp = (const float*)d_in[13];
    float* out = (float*)d_out;

    char* ws = (char*)d_ws;
    size_t off = 0;
    auto alloc = [&](size_t bytes) -> char* {
        char* p = ws + off; off += (bytes + 255) & ~(size_t)255; return p;
    };
    float*  cls    = (float*) alloc(7746048ull * 4);            // (8,16,246,246)
    float2* Z      = (float2*)alloc((size_t)64 * NFFT2 * 8);    // packed fp spectrum
    float2* PZ     = (float2*)alloc((size_t)64 * NFFT2 * 8);    // packed P spectrum
    float2* Zc     = (float2*)alloc((size_t)64 * NFFT2 * 8);    // filtered
    float2* Kf     = (float2*)alloc((size_t)8 * NFFT2 * 8);     // K spectrum per batch
    float*  pooled = (float*) alloc(1152 * 4);
    float*  kP     = (float*) alloc(1152 * 4);
    float2* tw     = (float2*)alloc(288 * 8);
    // h-chain buffers alias Z / PZ (used before any FFT work)
    float*  ha     = (float*)Z;
    float*  hb     = (float*)PZ;

    k_tw<<<1, 320, 0, stream>>>(tw);
    k_conv1x1_red<<<1892, 256, 0, stream>>>(x, w_red, b_red, cls);
    k_conv3x3<246, true ><<<466, 256, 0, stream>>>(cls, w_g1, b_g1, ha);
    k_conv3x3<244, true ><<<462, 256, 0, stream>>>(ha,  w_g2, b_g2, hb);
    k_conv3x3<242, false><<<450, 256, 0, stream>>>(hb,  w_g3, b_g3, ha);
    k_pool3<<<1152, 256, 0, stream>>>(ha, pooled);
    k_kernelP<<<128, 64, 0, stream>>>(pooled, w_g4, b_g4, kP);

    // PZ = fft2(packed psf(kernel_P))  (transposed spectral layout)
    k_psfP<<<20736, 256, 0, stream>>>(kP, PZ);
    k_fft_rows<false><<<4608, 256, 0, stream>>>(PZ, PZ, tw);
    k_transpose<<<64*45, 256, 0, stream>>>(PZ);
    k_fft_rows<false><<<4608, 256, 0, stream>>>(PZ, PZ, tw);

    // Kf = fft2(psf(kernel)) (8 batches, unpacked)
    k_psfK<<<2592, 256, 0, stream>>>(ker, Kf);
    k_fft_rows<false><<<576, 256, 0, stream>>>(Kf, Kf, tw);
    k_transpose<<<8*45, 256, 0, stream>>>(Kf);
    k_fft_rows<false><<<576, 256, 0, stream>>>(Kf, Kf, tw);

    // Z = fft2(packed edge-pad(cls))
    k_build_fp<<<20736, 256, 0, stream>>>(cls, Z);
    k_fft_rows<false><<<4608, 256, 0, stream>>>(Z, Z, tw);
    k_transpose<<<64*45, 256, 0, stream>>>(Z);
    k_fft_rows<false><<<4608, 256, 0, stream>>>(Z, Z, tw);

    // Zc = filtered (unpack, per-channel Wiener, repack)
    k_invker_packed<<<20736, 256, 0, stream>>>(Z, PZ, Kf, Zc);

    // deblur = ifft2(Zc)  -> spatial, re=ch 2pc, im=ch 2pc+1
    k_fft_rows<true><<<4608, 256, 0, stream>>>(Zc, Zc, tw);
    k_transpose<<<64*45, 256, 0, stream>>>(Zc);
    k_fft_rows<true><<<4608, 256, 0, stream>>>(Zc, Zc, tw);

    // out = conv1x1 16->64 fused with crop + 1/N^2 scale
    k_conv1x1_exp<<<1892, 256, 0, stream>>>(Zc, w_exp, b_exp, out);
}

// Round 3
// 364.904 us; speedup vs baseline: 2.0716x; 1.2941x over previous
//
#include <hip/hip_runtime.h>
#include <hip/hip_bf16.h>

// ---------- complex helpers ----------
__device__ inline float2 cadd(float2 a, float2 b){ return make_float2(a.x+b.x, a.y+b.y); }
__device__ inline float2 csub(float2 a, float2 b){ return make_float2(a.x-b.x, a.y-b.y); }
__device__ inline float2 cmul(float2 a, float2 b){
    return make_float2(fmaf(a.x,b.x,-a.y*b.y), fmaf(a.x,b.y,a.y*b.x));
}

#define NPIX 60516      // 246*246
#define NFFT 288
#define NFFT2 82944     // 288*288

// ---------- butterflies ----------
template<bool INV>
__device__ inline void bf4(float2 a0, float2 a1, float2 a2, float2 a3,
                           float2& b0, float2& b1, float2& b2, float2& b3) {
    float2 t0=cadd(a0,a2), t1=csub(a0,a2), t2=cadd(a1,a3), t3=csub(a1,a3);
    b0=cadd(t0,t2); b2=csub(t0,t2);
    if (!INV) { b1=make_float2(t1.x+t3.y, t1.y-t3.x); b3=make_float2(t1.x-t3.y, t1.y+t3.x); }
    else      { b1=make_float2(t1.x-t3.y, t1.y+t3.x); b3=make_float2(t1.x+t3.y, t1.y-t3.x); }
}
template<bool INV>
__device__ inline void bf3(float2 a0, float2 a1, float2 a2,
                           float2& b0, float2& b1, float2& b2) {
    const float d = INV ? 0.8660254037844386f : -0.8660254037844386f;
    float2 tt=cadd(a1,a2), u=csub(a1,a2);
    b0=cadd(a0,tt);
    b1=make_float2(a0.x-0.5f*tt.x - d*u.y, a0.y-0.5f*tt.y + d*u.x);
    b2=make_float2(a0.x-0.5f*tt.x + d*u.y, a0.y-0.5f*tt.y - d*u.x);
}

// ---------- row FFT core: 288-pt Stockham in LDS, one wave per row ----------
// result ends in *pX after return
template<bool INV>
__device__ inline void fft288_row(float2*& X, float2*& Y, int lane, const float2* __restrict__ tw) {
    auto TW = [&](int k) { float2 v = tw[k]; if (INV) v.y = -v.y; return v; };
    for (int p = lane; p < 72; p += 64) {
        float2 b0,b1,b2,b3;
        bf4<INV>(X[p], X[p+72], X[p+144], X[p+216], b0,b1,b2,b3);
        Y[4*p]=b0; Y[4*p+1]=cmul(b1,TW(p)); Y[4*p+2]=cmul(b2,TW(2*p)); Y[4*p+3]=cmul(b3,TW(3*p));
    }
    __syncthreads(); { float2* t=X; X=Y; Y=t; }
    for (int it = lane; it < 72; it += 64) {
        int p = it>>2, q = it&3, i0 = q+4*p;
        float2 b0,b1,b2,b3;
        bf4<INV>(X[i0], X[i0+72], X[i0+144], X[i0+216], b0,b1,b2,b3);
        int o = q+16*p;
        Y[o]=b0; Y[o+4]=cmul(b1,TW(4*p)); Y[o+8]=cmul(b2,TW(8*p)); Y[o+12]=cmul(b3,TW(12*p));
    }
    __syncthreads(); { float2* t=X; X=Y; Y=t; }
    for (int it = lane; it < 144; it += 64) {
        int p = it>>4, q = it&15, i0 = q+16*p;
        float2 a0=X[i0], a1=X[i0+144];
        int o = q+32*p;
        Y[o]=cadd(a0,a1); Y[o+16]=cmul(csub(a0,a1),TW(16*p));
    }
    __syncthreads(); { float2* t=X; X=Y; Y=t; }
    for (int it = lane; it < 96; it += 64) {
        int p = it>>5, q = it&31, i0 = q+32*p;
        float2 b0,b1,b2;
        bf3<INV>(X[i0], X[i0+96], X[i0+192], b0,b1,b2);
        int o = q+96*p;
        Y[o]=b0; Y[o+32]=cmul(b1,TW(32*p)); Y[o+64]=cmul(b2,TW(64*p));
    }
    __syncthreads(); { float2* t=X; X=Y; Y=t; }
    for (int q = lane; q < 96; q += 64) {
        float2 b0,b1,b2;
        bf3<INV>(X[q], X[q+96], X[q+192], b0,b1,b2);
        Y[q]=b0; Y[q+96]=b1; Y[q+192]=b2;
    }
    __syncthreads(); { float2* t=X; X=Y; Y=t; }
}

// ---------- twiddle table ----------
__global__ void k_tw(float2* tw) {
    int k = threadIdx.x;
    if (k < NFFT) {
        double ang = -2.0 * 3.14159265358979323846 * (double)k / (double)NFFT;
        tw[k] = make_float2((float)cos(ang), (float)sin(ang));
    }
}

// ---------- 1x1 conv 64->16 ----------
__global__ __launch_bounds__(256) void k_conv1x1_red(const float* __restrict__ x,
        const float* __restrict__ w, const float* __restrict__ bias, float* __restrict__ out) {
    int idx = blockIdx.x * 256 + threadIdx.x;
    if (idx >= 8 * NPIX) return;
    int b = idx / NPIX, p = idx % NPIX;
    const float* xb = x + (size_t)b * 64 * NPIX + p;
    float acc[16];
    #pragma unroll
    for (int co = 0; co < 16; co++) acc[co] = bias[co];
    for (int ci = 0; ci < 64; ci++) {
        float v = xb[(size_t)ci * NPIX];
        #pragma unroll
        for (int co = 0; co < 16; co++) acc[co] = fmaf(w[co*64+ci], v, acc[co]);
    }
    float* ob = out + (size_t)b * 16 * NPIX + p;
    #pragma unroll
    for (int co = 0; co < 16; co++) ob[(size_t)co*NPIX] = acc[co];
}

// ---------- 3x3 valid conv 16->16, 4 px/thread, scalar weights ----------
template<int HIN, bool LEAKY>
__global__ __launch_bounds__(256) void k_conv3x3(const float* __restrict__ in,
        const float* __restrict__ w, const float* __restrict__ bias, float* __restrict__ out) {
    const int HOUT = HIN - 2;
    const int GX = (HOUT + 3) / 4;
    int idx = blockIdx.x * 256 + threadIdx.x;
    if (idx >= 8 * HOUT * GX) return;
    int b  = idx / (HOUT * GX);
    int r  = idx % (HOUT * GX);
    int oy = r / GX;
    int ox0 = (r % GX) * 4;

    float acc[16][4];
    #pragma unroll
    for (int co = 0; co < 16; co++) {
        float bb = bias[co];
        #pragma unroll
        for (int px = 0; px < 4; px++) acc[co][px] = bb;
    }
    const float* ib = in + (size_t)b * 16 * HIN * HIN + (size_t)oy * HIN;
    for (int ci = 0; ci < 16; ci++) {
        const float* ic = ib + (size_t)ci * HIN * HIN;
        #pragma unroll
        for (int ky = 0; ky < 3; ky++) {
            float in6[6];
            #pragma unroll
            for (int j = 0; j < 6; j++) {
                int xx = ox0 + j;
                if (HOUT % 4 != 0) { if (xx > HIN - 1) xx = HIN - 1; }
                in6[j] = ic[ky * HIN + xx];
            }
            #pragma unroll
            for (int kx = 0; kx < 3; kx++) {
                #pragma unroll
                for (int co = 0; co < 16; co++) {
                    float wv = w[co*144 + ci*9 + ky*3 + kx];
                    #pragma unroll
                    for (int px = 0; px < 4; px++)
                        acc[co][px] = fmaf(wv, in6[px + kx], acc[co][px]);
                }
            }
        }
    }
    float* ob = out + (size_t)b * 16 * HOUT * HOUT + (size_t)oy * HOUT + ox0;
    #pragma unroll
    for (int co = 0; co < 16; co++) {
        #pragma unroll
        for (int px = 0; px < 4; px++) {
            if (HOUT % 4 == 0 || ox0 + px < HOUT) {
                float v = acc[co][px];
                if (LEAKY) v = (v >= 0.f) ? v : 0.1f * v;
                ob[(size_t)co * HOUT * HOUT + px] = v;
            }
        }
    }
}

// ---------- adaptive pool (240,240)->(3,3) ----------
__global__ __launch_bounds__(256) void k_pool3(const float* __restrict__ in, float* __restrict__ out) {
    int bc = blockIdx.x;
    int cell = bc % 9, ch = bc / 9;
    int by = cell / 3, bx = cell % 3;
    const float* base = in + (size_t)ch * 240*240 + (size_t)by*80*240 + bx*80;
    float s = 0.f;
    for (int i = threadIdx.x; i < 6400; i += 256) {
        int r = i / 80, c = i % 80;
        s += base[r*240 + c];
    }
    __shared__ float red[256];
    red[threadIdx.x] = s; __syncthreads();
    for (int st = 128; st > 0; st >>= 1) {
        if (threadIdx.x < st) red[threadIdx.x] += red[threadIdx.x+st];
        __syncthreads();
    }
    if (threadIdx.x == 0) out[bc] = red[0] * (1.f/6400.f);
}

// ---------- kernel_P: 1x1 conv (16->16) + exp + spatial-mean subtraction ----------
__global__ void k_kernelP(const float* __restrict__ pooled, const float* __restrict__ w,
                          const float* __restrict__ bias, float* __restrict__ out) {
    int b = blockIdx.x / 16, co = blockIdx.x % 16;
    __shared__ float vals[9];
    int t = threadIdx.x;
    if (t < 9) {
        float a = bias[co];
        for (int ci = 0; ci < 16; ci++) a += pooled[(b*16+ci)*9 + t] * w[co*16+ci];
        vals[t] = expf(a);
    }
    __syncthreads();
    if (t < 9) {
        float m = 0.f;
        #pragma unroll
        for (int i = 0; i < 9; i++) m += vals[i];
        m *= (1.f/9.f);
        out[(b*16+co)*9 + t] = vals[t] - m;
    }
}

// ---------- psf builder for K (8 batch kernels) ----------
__global__ __launch_bounds__(256) void k_psfK(const float* __restrict__ ker, float2* __restrict__ Kf) {
    int idx = blockIdx.x*256 + threadIdx.x;
    if (idx >= 8*NFFT2) return;
    int pos = idx % NFFT2, b = idx / NFFT2;
    int y = pos / NFFT, x = pos % NFFT;
    int ry = (y < 11) ? y+10 : ((y >= 278) ? y-278 : -1);
    int rx = (x < 11) ? x+10 : ((x >= 278) ? x-278 : -1);
    float v = (ry >= 0 && rx >= 0) ? ker[b*441 + ry*21 + rx] : 0.f;
    Kf[idx] = make_float2(v, 0.f);
}

// ---------- plain row FFT (for Kf) ----------
template<bool INV>
__global__ __launch_bounds__(256) void k_fft_rows(float2* __restrict__ M, const float2* __restrict__ tw) {
    __shared__ float2 A[4][NFFT];
    __shared__ float2 B[4][NFFT];
    int t = threadIdx.x, w = t >> 6, lane = t & 63;
    size_t row = (size_t)blockIdx.x*4 + w;
    float2* X = A[w]; float2* Y = B[w];
    float2* s = M + row*NFFT;
    for (int j = lane; j < NFFT; j += 64) X[j] = s[j];
    __syncthreads();
    fft288_row<INV>(X, Y, lane, tw);
    for (int j = lane; j < NFFT; j += 64) s[j] = X[j];
}

// ---------- forward row FFT fused with packed edge-pad load ----------
__global__ __launch_bounds__(256) void k_fft_rows_pad(const float* __restrict__ cls,
        float2* __restrict__ Z, const float2* __restrict__ tw) {
    __shared__ float2 A[4][NFFT];
    __shared__ float2 B[4][NFFT];
    int t = threadIdx.x, w = t >> 6, lane = t & 63;
    size_t row = (size_t)blockIdx.x*4 + w;
    int pc = (int)(row / NFFT), y = (int)(row % NFFT);
    int iy = min(max(y-21, 0), 245);
    const float* c0 = cls + (size_t)(2*pc)*NPIX + (size_t)iy*246;
    float2* X = A[w]; float2* Y = B[w];
    for (int j = lane; j < NFFT; j += 64) {
        int ix = min(max(j-21, 0), 245);
        X[j] = make_float2(c0[ix], c0[NPIX+ix]);
    }
    __syncthreads();
    fft288_row<false>(X, Y, lane, tw);
    float2* d = Z + row*NFFT;
    for (int j = lane; j < NFFT; j += 64) d[j] = X[j];
}

// ---------- inverse row FFT fused with crop + scale (writes real planes) ----------
__global__ __launch_bounds__(256) void k_ifft_rows_crop(const float2* __restrict__ Z,
        float* __restrict__ clear, const float2* __restrict__ tw) {
    __shared__ float2 A[4][NFFT];
    __shared__ float2 B[4][NFFT];
    int t = threadIdx.x, w = t >> 6, lane = t & 63;
    int ch = blockIdx.x / 62;
    int rseq = (blockIdx.x % 62)*4 + w;       // 0..245 valid
    bool valid = rseq < 246;
    int y = rseq + 21;
    float2* X = A[w]; float2* Y = B[w];
    if (valid) {
        const float2* s = Z + (size_t)ch*NFFT2 + (size_t)y*NFFT;
        for (int j = lane; j < NFFT; j += 64) X[j] = s[j];
    }
    __syncthreads();
    fft288_row<true>(X, Y, lane, tw);
    if (valid) {
        const float sc = 1.0f / 82944.0f;
        float* o0 = clear + (size_t)(2*ch)*NPIX + (size_t)rseq*246;
        for (int j = lane; j < 246; j += 64) {
            float2 v = X[j+21];
            o0[j]        = v.x * sc;
            o0[NPIX + j] = v.y * sc;
        }
    }
}

// ---------- column FFT: 8 columns per block, in place ----------
template<bool INV>
__global__ __launch_bounds__(256) void k_fft_cols(float2* __restrict__ M, const float2* __restrict__ tw) {
    __shared__ float2 Abuf[NFFT*9];
    __shared__ float2 Bbuf[NFFT*9];
    int t = threadIdx.x, c = t & 7, w = t >> 3;    // w in [0,32)
    int ch = blockIdx.x / 36, cg = blockIdx.x % 36;
    float2* base = M + (size_t)ch * NFFT2 + cg*8 + c;
    float2* X = Abuf; float2* Y = Bbuf;
    for (int r = w; r < NFFT; r += 32) X[r*9 + c] = base[(size_t)r * NFFT];
    __syncthreads();
    auto TW = [&](int k) { float2 v = tw[k]; if (INV) v.y = -v.y; return v; };
    for (int p = w; p < 72; p += 32) {
        float2 b0,b1,b2,b3;
        bf4<INV>(X[p*9+c], X[(p+72)*9+c], X[(p+144)*9+c], X[(p+216)*9+c], b0,b1,b2,b3);
        Y[(4*p)*9+c]=b0; Y[(4*p+1)*9+c]=cmul(b1,TW(p));
        Y[(4*p+2)*9+c]=cmul(b2,TW(2*p)); Y[(4*p+3)*9+c]=cmul(b3,TW(3*p));
    }
    __syncthreads(); { float2* tp=X; X=Y; Y=tp; }
    for (int it = w; it < 72; it += 32) {
        int p = it>>2, q = it&3, i0 = q+4*p;
        float2 b0,b1,b2,b3;
        bf4<INV>(X[i0*9+c], X[(i0+72)*9+c], X[(i0+144)*9+c], X[(i0+216)*9+c], b0,b1,b2,b3);
        int o = q+16*p;
        Y[o*9+c]=b0; Y[(o+4)*9+c]=cmul(b1,TW(4*p));
        Y[(o+8)*9+c]=cmul(b2,TW(8*p)); Y[(o+12)*9+c]=cmul(b3,TW(12*p));
    }
    __syncthreads(); { float2* tp=X; X=Y; Y=tp; }
    for (int it = w; it < 144; it += 32) {
        int p = it>>4, q = it&15, i0 = q+16*p;
        float2 a0=X[i0*9+c], a1=X[(i0+144)*9+c];
        int o = q+32*p;
        Y[o*9+c]=cadd(a0,a1); Y[(o+16)*9+c]=cmul(csub(a0,a1),TW(16*p));
    }
    __syncthreads(); { float2* tp=X; X=Y; Y=tp; }
    for (int it = w; it < 96; it += 32) {
        int p = it>>5, q = it&31, i0 = q+32*p;
        float2 b0,b1,b2;
        bf3<INV>(X[i0*9+c], X[(i0+96)*9+c], X[(i0+192)*9+c], b0,b1,b2);
        int o = q+96*p;
        Y[o*9+c]=b0; Y[(o+32)*9+c]=cmul(b1,TW(32*p)); Y[(o+64)*9+c]=cmul(b2,TW(64*p));
    }
    __syncthreads(); { float2* tp=X; X=Y; Y=tp; }
    for (int q = w; q < 96; q += 32) {
        float2 b0,b1,b2;
        bf3<INV>(X[q*9+c], X[(q+96)*9+c], X[(q+192)*9+c], b0,b1,b2);
        Y[q*9+c]=b0; Y[(q+96)*9+c]=b1; Y[(q+192)*9+c]=b2;
    }
    __syncthreads(); { float2* tp=X; X=Y; Y=tp; }
    for (int r = w; r < NFFT; r += 32) base[(size_t)r * NFFT] = X[r*9 + c];
}

// ---------- Wiener filter, Hermitian-pair in-place, analytic P ----------
__global__ __launch_bounds__(256) void k_invker(float2* __restrict__ Z, const float* __restrict__ kP,
        const float2* __restrict__ Kf, const float2* __restrict__ tw) {
    int pc = blockIdx.x / 164;
    int q  = (blockIdx.x % 164) * 256 + threadIdx.x;
    if (q >= 145*288) return;
    int yh = q / 288, x = q % 288;
    bool self = false;
    if (yh == 0 || yh == 144) {
        if (x == 0 || x == 144) self = true;
        else if (x > 144) return;
    }
    int y = yh;
    int my = (NFFT - y) % NFFT;
    int mx = (NFFT - x) % NFFT;
    size_t basez = (size_t)pc * NFFT2;
    int pos = y*NFFT + x, mpos = my*NFFT + mx;
    float2 zk = Z[basez + pos];
    float2 zm = self ? zk : Z[basez + mpos];
    int b = pc >> 3;
    float2 K = Kf[(size_t)b*NFFT2 + pos];
    float2 wy = tw[y], wx = tw[x];
    const float* pA = kP + (size_t)(2*pc)*9;
    const float* pB = pA + 9;
    // P(u,v) = sum_{a,b in {-1,0,1}} p[1+a][1+b] wy^a wx^b
    auto otf3 = [&](const float* p9) {
        float2 R0 = make_float2(p9[1] + (p9[0]+p9[2])*wx.x, (p9[2]-p9[0])*wx.y);
        float2 R1 = make_float2(p9[4] + (p9[3]+p9[5])*wx.x, (p9[5]-p9[3])*wx.y);
        float2 R2 = make_float2(p9[7] + (p9[6]+p9[8])*wx.x, (p9[8]-p9[6])*wx.y);
        float2 P;
        P.x = R1.x + wy.x*(R0.x+R2.x) - wy.y*(R2.y-R0.y);
        P.y = R1.y + wy.x*(R0.y+R2.y) + wy.y*(R2.x-R0.x);
        return P;
    };
    float2 Pa = otf3(pA);
    float2 Pb = otf3(pB);
    // unpack two real-channel spectra
    float2 A_ = make_float2(0.5f*(zk.x+zm.x),  0.5f*(zk.y-zm.y));
    float2 B_ = make_float2(0.5f*(zk.y+zm.y), -0.5f*(zk.x-zm.x));
    float kk = K.x*K.x + K.y*K.y;
    float ra = 1.0f / (kk + Pa.x*Pa.x + Pa.y*Pa.y);
    float rb = 1.0f / (kk + Pb.x*Pb.x + Pb.y*Pb.y);
    float2 Ha = make_float2(K.x*ra, -K.y*ra);
    float2 Hb = make_float2(K.x*rb, -K.y*rb);
    float2 Fa = cmul(Ha, A_);
    float2 Fb = cmul(Hb, B_);
    Z[basez + pos] = make_float2(Fa.x - Fb.y, Fa.y + Fb.x);
    if (!self)
        Z[basez + mpos] = make_float2(Fa.x + Fb.y, Fb.x - Fa.y);  // conj(Fa)+i*conj(Fb)
}

// ---------- 1x1 conv 16->64 ----------
__global__ __launch_bounds__(256) void k_conv1x1_exp(const float* __restrict__ clear,
        const float* __restrict__ w, const float* __restrict__ bias, float* __restrict__ out) {
    int idx = blockIdx.x * 256 + threadIdx.x;
    if (idx >= 8 * NPIX) return;
    int b = idx / NPIX, p = idx % NPIX;
    const float* cb = clear + (size_t)b * 16 * NPIX + p;
    float v[16];
    #pragma unroll
    for (int ci = 0; ci < 16; ci++) v[ci] = cb[(size_t)ci*NPIX];
    float* ob = out + (size_t)b * 64 * NPIX + p;
    #pragma unroll
    for (int co = 0; co < 64; co++) {
        float a = bias[co];
        #pragma unroll
        for (int ci = 0; ci < 16; ci++) a = fmaf(w[co*16+ci], v[ci], a);
        ob[(size_t)co*NPIX] = a;
    }
}

extern "C" void kernel_launch(void* const* d_in, const int* in_sizes, int n_in,
                              void* d_out, int out_size, void* d_ws, size_t ws_size,
                              hipStream_t stream) {
    const float* x     = (const float*)d_in[0];
    const float* ker   = (const float*)d_in[1];
    const float* w_red = (const float*)d_in[2];
    const float* b_red = (const float*)d_in[3];
    const float* w_g1  = (const float*)d_in[4];
    const float* b_g1  = (const float*)d_in[5];
    const float* w_g2  = (const float*)d_in[6];
    const float* b_g2  = (const float*)d_in[7];
    const float* w_g3  = (const float*)d_in[8];
    const float* b_g3  = (const float*)d_in[9];
    const float* w_g4  = (const float*)d_in[10];
    const float* b_g4  = (const float*)d_in[11];
    const float* w_exp = (const float*)d_in[12];
    const float* b_exp = (const float*)d_in[13];
    float* out = (float*)d_out;

    char* ws = (char*)d_ws;
    size_t off = 0;
    auto alloc = [&](size_t bytes) -> char* {
        char* p = ws + off; off += (bytes + 255) & ~(size_t)255; return p;
    };
    float*  cls    = (float*) alloc(7746048ull * 4);            // (8,16,246,246)
    float2* Z      = (float2*)alloc((size_t)64 * NFFT2 * 8);    // packed spectrum / work
    float*  clear  = (float*) alloc(7746048ull * 4);            // (8,16,246,246)
    float2* Kf     = (float2*)alloc((size_t)8 * NFFT2 * 8);     // K spectrum per batch
    float*  pooled = (float*) alloc(1152 * 4);
    float*  kP     = (float*) alloc(1152 * 4);
    float2* tw     = (float2*)alloc(288 * 8);
    // h-chain aliases (consumed before Z / clear are written)
    float*  ha     = (float*)Z;
    float*  hb     = (float*)clear;

    k_tw<<<1, 320, 0, stream>>>(tw);
    k_conv1x1_red<<<1892, 256, 0, stream>>>(x, w_red, b_red, cls);
    k_conv3x3<246, true ><<<466, 256, 0, stream>>>(cls, w_g1, b_g1, ha);
    k_conv3x3<244, true ><<<462, 256, 0, stream>>>(ha,  w_g2, b_g2, hb);
    k_conv3x3<242, false><<<450, 256, 0, stream>>>(hb,  w_g3, b_g3, ha);
    k_pool3<<<1152, 256, 0, stream>>>(ha, pooled);
    k_kernelP<<<128, 64, 0, stream>>>(pooled, w_g4, b_g4, kP);

    // Kf = fft2(psf(kernel)) — natural layout (rows then cols)
    k_psfK<<<2592, 256, 0, stream>>>(ker, Kf);
    k_fft_rows<false><<<576, 256, 0, stream>>>(Kf, tw);
    k_fft_cols<false><<<288, 256, 0, stream>>>(Kf, tw);

    // Z = fft2(packed edge-pad(cls)) — pad fused into row pass
    k_fft_rows_pad<<<4608, 256, 0, stream>>>(cls, Z, tw);
    k_fft_cols<false><<<2304, 256, 0, stream>>>(Z, tw);

    // Wiener filter in place (Hermitian pairs, analytic P-OTF)
    k_invker<<<10496, 256, 0, stream>>>(Z, kP, Kf, tw);

    // inverse FFT: cols in place, then rows fused with crop+scale
    k_fft_cols<true><<<2304, 256, 0, stream>>>(Z, tw);
    k_ifft_rows_crop<<<3968, 256, 0, stream>>>(Z, clear, tw);

    // out = conv1x1 16->64
    k_conv1x1_exp<<<1892, 256, 0, stream>>>(clear, w_exp, b_exp, out);
}

// Round 5
// 357.692 us; speedup vs baseline: 2.1134x; 1.0202x over previous
//
#include <hip/hip_runtime.h>
#include <hip/hip_bf16.h>

// ---------- complex helpers ----------
__device__ inline float2 cadd(float2 a, float2 b){ return make_float2(a.x+b.x, a.y+b.y); }
__device__ inline float2 csub(float2 a, float2 b){ return make_float2(a.x-b.x, a.y-b.y); }
__device__ inline float2 cmul(float2 a, float2 b){
    return make_float2(fmaf(a.x,b.x,-a.y*b.y), fmaf(a.x,b.y,a.y*b.x));
}

#define NPIX 60516      // 246*246
#define NFFT 288
#define NFFT2 82944     // 288*288

// ---------- butterflies ----------
template<bool INV>
__device__ inline void bf4(float2 a0, float2 a1, float2 a2, float2 a3,
                           float2& b0, float2& b1, float2& b2, float2& b3) {
    float2 t0=cadd(a0,a2), t1=csub(a0,a2), t2=cadd(a1,a3), t3=csub(a1,a3);
    b0=cadd(t0,t2); b2=csub(t0,t2);
    if (!INV) { b1=make_float2(t1.x+t3.y, t1.y-t3.x); b3=make_float2(t1.x-t3.y, t1.y+t3.x); }
    else      { b1=make_float2(t1.x-t3.y, t1.y+t3.x); b3=make_float2(t1.x+t3.y, t1.y-t3.x); }
}
template<bool INV>
__device__ inline void bf3(float2 a0, float2 a1, float2 a2,
                           float2& b0, float2& b1, float2& b2) {
    const float d = INV ? 0.8660254037844386f : -0.8660254037844386f;
    float2 tt=cadd(a1,a2), u=csub(a1,a2);
    b0=cadd(a0,tt);
    b1=make_float2(a0.x-0.5f*tt.x - d*u.y, a0.y-0.5f*tt.y + d*u.x);
    b2=make_float2(a0.x-0.5f*tt.x + d*u.y, a0.y-0.5f*tt.y - d*u.x);
}

// ---------- 288-pt Stockham core, contiguous layout (one wave per row) ----------
template<bool INV>
__device__ inline void fft288_row(float2*& X, float2*& Y, int lane, const float2* __restrict__ tw) {
    auto TW = [&](int k) { float2 v = tw[k]; if (INV) v.y = -v.y; return v; };
    for (int p = lane; p < 72; p += 64) {
        float2 b0,b1,b2,b3;
        bf4<INV>(X[p], X[p+72], X[p+144], X[p+216], b0,b1,b2,b3);
        Y[4*p]=b0; Y[4*p+1]=cmul(b1,TW(p)); Y[4*p+2]=cmul(b2,TW(2*p)); Y[4*p+3]=cmul(b3,TW(3*p));
    }
    __syncthreads(); { float2* t=X; X=Y; Y=t; }
    for (int it = lane; it < 72; it += 64) {
        int p = it>>2, q = it&3, i0 = q+4*p;
        float2 b0,b1,b2,b3;
        bf4<INV>(X[i0], X[i0+72], X[i0+144], X[i0+216], b0,b1,b2,b3);
        int o = q+16*p;
        Y[o]=b0; Y[o+4]=cmul(b1,TW(4*p)); Y[o+8]=cmul(b2,TW(8*p)); Y[o+12]=cmul(b3,TW(12*p));
    }
    __syncthreads(); { float2* t=X; X=Y; Y=t; }
    for (int it = lane; it < 144; it += 64) {
        int p = it>>4, q = it&15, i0 = q+16*p;
        float2 a0=X[i0], a1=X[i0+144];
        int o = q+32*p;
        Y[o]=cadd(a0,a1); Y[o+16]=cmul(csub(a0,a1),TW(16*p));
    }
    __syncthreads(); { float2* t=X; X=Y; Y=t; }
    for (int it = lane; it < 96; it += 64) {
        int p = it>>5, q = it&31, i0 = q+32*p;
        float2 b0,b1,b2;
        bf3<INV>(X[i0], X[i0+96], X[i0+192], b0,b1,b2);
        int o = q+96*p;
        Y[o]=b0; Y[o+32]=cmul(b1,TW(32*p)); Y[o+64]=cmul(b2,TW(64*p));
    }
    __syncthreads(); { float2* t=X; X=Y; Y=t; }
    for (int q = lane; q < 96; q += 64) {
        float2 b0,b1,b2;
        bf3<INV>(X[q], X[q+96], X[q+192], b0,b1,b2);
        Y[q]=b0; Y[q+96]=b1; Y[q+192]=b2;
    }
    __syncthreads(); { float2* t=X; X=Y; Y=t; }
}

// ---------- 288-pt Stockham core, stride-9 layout (8 lanes share, 32 rows/thread-group) ----------
template<bool INV>
__device__ inline void fft288_s9(float2*& X, float2*& Y, int w, int c, const float2* __restrict__ tw) {
    auto TW = [&](int k) { float2 v = tw[k]; if (INV) v.y = -v.y; return v; };
    #define SIX(i) ((i)*9 + c)
    for (int p = w; p < 72; p += 32) {
        float2 b0,b1,b2,b3;
        bf4<INV>(X[SIX(p)], X[SIX(p+72)], X[SIX(p+144)], X[SIX(p+216)], b0,b1,b2,b3);
        Y[SIX(4*p)]=b0; Y[SIX(4*p+1)]=cmul(b1,TW(p));
        Y[SIX(4*p+2)]=cmul(b2,TW(2*p)); Y[SIX(4*p+3)]=cmul(b3,TW(3*p));
    }
    __syncthreads(); { float2* t=X; X=Y; Y=t; }
    for (int it = w; it < 72; it += 32) {
        int p = it>>2, q = it&3, i0 = q+4*p;
        float2 b0,b1,b2,b3;
        bf4<INV>(X[SIX(i0)], X[SIX(i0+72)], X[SIX(i0+144)], X[SIX(i0+216)], b0,b1,b2,b3);
        int o = q+16*p;
        Y[SIX(o)]=b0; Y[SIX(o+4)]=cmul(b1,TW(4*p));
        Y[SIX(o+8)]=cmul(b2,TW(8*p)); Y[SIX(o+12)]=cmul(b3,TW(12*p));
    }
    __syncthreads(); { float2* t=X; X=Y; Y=t; }
    for (int it = w; it < 144; it += 32) {
        int p = it>>4, q = it&15, i0 = q+16*p;
        float2 a0=X[SIX(i0)], a1=X[SIX(i0+144)];
        int o = q+32*p;
        Y[SIX(o)]=cadd(a0,a1); Y[SIX(o+16)]=cmul(csub(a0,a1),TW(16*p));
    }
    __syncthreads(); { float2* t=X; X=Y; Y=t; }
    for (int it = w; it < 96; it += 32) {
        int p = it>>5, q = it&31, i0 = q+32*p;
        float2 b0,b1,b2;
        bf3<INV>(X[SIX(i0)], X[SIX(i0+96)], X[SIX(i0+192)], b0,b1,b2);
        int o = q+96*p;
        Y[SIX(o)]=b0; Y[SIX(o+32)]=cmul(b1,TW(32*p)); Y[SIX(o+64)]=cmul(b2,TW(64*p));
    }
    __syncthreads(); { float2* t=X; X=Y; Y=t; }
    for (int q = w; q < 96; q += 32) {
        float2 b0,b1,b2;
        bf3<INV>(X[SIX(q)], X[SIX(q+96)], X[SIX(q+192)], b0,b1,b2);
        Y[SIX(q)]=b0; Y[SIX(q+96)]=b1; Y[SIX(q+192)]=b2;
    }
    __syncthreads(); { float2* t=X; X=Y; Y=t; }
    #undef SIX
}

// ---------- prep: twiddles + zero pooled ----------
__global__ void k_tw(float2* tw, float* pooled) {
    int t = threadIdx.x;
    if (t < NFFT) {
        double ang = -2.0 * 3.14159265358979323846 * (double)t / (double)NFFT;
        tw[t] = make_float2((float)cos(ang), (float)sin(ang));
    }
    for (int i = t; i < 1152; i += 320) pooled[i] = 0.f;
}

// ---------- 1x1 conv 64->16 ----------
__global__ __launch_bounds__(256) void k_conv1x1_red(const float* __restrict__ x,
        const float* __restrict__ w, const float* __restrict__ bias, float* __restrict__ out) {
    int idx = blockIdx.x * 256 + threadIdx.x;
    if (idx >= 8 * NPIX) return;
    int b = idx / NPIX, p = idx % NPIX;
    const float* xb = x + (size_t)b * 64 * NPIX + p;
    float acc[16];
    #pragma unroll
    for (int co = 0; co < 16; co++) acc[co] = bias[co];
    for (int ci = 0; ci < 64; ci++) {
        float v = xb[(size_t)ci * NPIX];
        #pragma unroll
        for (int co = 0; co < 16; co++) acc[co] = fmaf(w[co*64+ci], v, acc[co]);
    }
    float* ob = out + (size_t)b * 16 * NPIX + p;
    #pragma unroll
    for (int co = 0; co < 16; co++) ob[(size_t)co*NPIX] = acc[co];
}

// ---------- 3x3 valid conv 16->16, 4 px/thread, scalar weights ----------
template<int HIN, bool LEAKY>
__global__ __launch_bounds__(256) void k_conv3x3(const float* __restrict__ in,
        const float* __restrict__ w, const float* __restrict__ bias, float* __restrict__ out) {
    const int HOUT = HIN - 2;
    const int GX = (HOUT + 3) / 4;
    int idx = blockIdx.x * 256 + threadIdx.x;
    if (idx >= 8 * HOUT * GX) return;
    int b  = idx / (HOUT * GX);
    int r  = idx % (HOUT * GX);
    int oy = r / GX;
    int ox0 = (r % GX) * 4;

    float acc[16][4];
    #pragma unroll
    for (int co = 0; co < 16; co++) {
        float bb = bias[co];
        #pragma unroll
        for (int px = 0; px < 4; px++) acc[co][px] = bb;
    }
    const float* ib = in + (size_t)b * 16 * HIN * HIN + (size_t)oy * HIN;
    for (int ci = 0; ci < 16; ci++) {
        const float* ic = ib + (size_t)ci * HIN * HIN;
        #pragma unroll
        for (int ky = 0; ky < 3; ky++) {
            float in6[6];
            #pragma unroll
            for (int j = 0; j < 6; j++) {
                int xx = ox0 + j;
                if (HOUT % 4 != 0) { if (xx > HIN - 1) xx = HIN - 1; }
                in6[j] = ic[ky * HIN + xx];
            }
            #pragma unroll
            for (int kx = 0; kx < 3; kx++) {
                #pragma unroll
                for (int co = 0; co < 16; co++) {
                    float wv = w[co*144 + ci*9 + ky*3 + kx];
                    #pragma unroll
                    for (int px = 0; px < 4; px++)
                        acc[co][px] = fmaf(wv, in6[px + kx], acc[co][px]);
                }
            }
        }
    }
    float* ob = out + (size_t)b * 16 * HOUT * HOUT + (size_t)oy * HOUT + ox0;
    #pragma unroll
    for (int co = 0; co < 16; co++) {
        #pragma unroll
        for (int px = 0; px < 4; px++) {
            if (HOUT % 4 == 0 || ox0 + px < HOUT) {
                float v = acc[co][px];
                if (LEAKY) v = (v >= 0.f) ? v : 0.1f * v;
                ob[(size_t)co * HOUT * HOUT + px] = v;
            }
        }
    }
}

// ---------- 3x3 conv (242->240) fused with adaptive pool -> pooled (raw sums) ----------
__global__ __launch_bounds__(256) void k_conv3x3_pool(const float* __restrict__ in,
        const float* __restrict__ w, const float* __restrict__ bias, float* __restrict__ pooled) {
    const int HIN = 242, GX = 60;
    __shared__ float cs[144];
    int t = threadIdx.x;
    int b = blockIdx.x / 57;
    int r = (blockIdx.x % 57) * 256 + t;
    bool valid = r < 14400;
    float partial[16];
    int cell = 0;
    if (valid) {
        int oy = r / GX, ox0 = (r % GX) * 4;
        cell = (oy / 80) * 3 + (ox0 / 80);
        float acc[16][4];
        #pragma unroll
        for (int co = 0; co < 16; co++) {
            float bb = bias[co];
            #pragma unroll
            for (int px = 0; px < 4; px++) acc[co][px] = bb;
        }
        const float* ib = in + (size_t)b * 16 * HIN * HIN + (size_t)oy * HIN;
        for (int ci = 0; ci < 16; ci++) {
            const float* ic = ib + (size_t)ci * HIN * HIN;
            #pragma unroll
            for (int ky = 0; ky < 3; ky++) {
                float in6[6];
                #pragma unroll
                for (int j = 0; j < 6; j++) in6[j] = ic[ky * HIN + ox0 + j];
                #pragma unroll
                for (int kx = 0; kx < 3; kx++) {
                    #pragma unroll
                    for (int co = 0; co < 16; co++) {
                        float wv = w[co*144 + ci*9 + ky*3 + kx];
                        #pragma unroll
                        for (int px = 0; px < 4; px++)
                            acc[co][px] = fmaf(wv, in6[px + kx], acc[co][px]);
                    }
                }
            }
        }
        #pragma unroll
        for (int co = 0; co < 16; co++)
            partial[co] = (acc[co][0] + acc[co][1]) + (acc[co][2] + acc[co][3]);
    }
    if (t < 144) cs[t] = 0.f;
    __syncthreads();
    if (valid) {
        #pragma unroll
        for (int co = 0; co < 16; co++) atomicAdd(&cs[co*9 + cell], partial[co]);
    }
    __syncthreads();
    if (t < 144) atomicAdd(&pooled[b*144 + t], cs[t]);
}

// ---------- kernel_P: 1x1 conv (16->16) + exp + spatial-mean subtraction ----------
__global__ void k_kernelP(const float* __restrict__ pooled, const float* __restrict__ w,
                          const float* __restrict__ bias, float* __restrict__ out) {
    int b = blockIdx.x / 16, co = blockIdx.x % 16;
    __shared__ float vals[9];
    int t = threadIdx.x;
    if (t < 9) {
        float a = 0.f;
        for (int ci = 0; ci < 16; ci++) a += pooled[(b*16+ci)*9 + t] * w[co*16+ci];
        vals[t] = expf(bias[co] + a * (1.f/6400.f));
    }
    __syncthreads();
    if (t < 9) {
        float m = 0.f;
        #pragma unroll
        for (int i = 0; i < 9; i++) m += vals[i];
        m *= (1.f/9.f);
        out[(b*16+co)*9 + t] = vals[t] - m;
    }
}

// ---------- psf builder for K, TRANSPOSED: KfT[b][u][v] = psf[b][v][u] ----------
__global__ __launch_bounds__(256) void k_psfKT(const float* __restrict__ ker, float2* __restrict__ KfT) {
    int idx = blockIdx.x*256 + threadIdx.x;
    if (idx >= 8*NFFT2) return;
    int pos = idx % NFFT2, b = idx / NFFT2;
    int u = pos / NFFT, v = pos % NFFT;
    int ry = (v < 11) ? v+10 : ((v >= 278) ? v-278 : -1);
    int rx = (u < 11) ? u+10 : ((u >= 278) ? u-278 : -1);
    float val = (ry >= 0 && rx >= 0) ? ker[b*441 + ry*21 + rx] : 0.f;
    KfT[idx] = make_float2(val, 0.f);
}

// ---------- plain row FFT (for KfT) ----------
template<bool INV>
__global__ __launch_bounds__(256) void k_fft_rows(float2* __restrict__ M, const float2* __restrict__ tw) {
    __shared__ float2 A[4][NFFT];
    __shared__ float2 B[4][NFFT];
    int t = threadIdx.x, w = t >> 6, lane = t & 63;
    size_t row = (size_t)blockIdx.x*4 + w;
    float2* X = A[w]; float2* Y = B[w];
    float2* s = M + row*NFFT;
    for (int j = lane; j < NFFT; j += 64) X[j] = s[j];
    __syncthreads();
    fft288_row<INV>(X, Y, lane, tw);
    for (int j = lane; j < NFFT; j += 64) s[j] = X[j];
}

// ---------- plain col FFT (for KfT) ----------
template<bool INV>
__global__ __launch_bounds__(256) void k_fft_cols(float2* __restrict__ M, const float2* __restrict__ tw) {
    __shared__ float2 Abuf[NFFT*9];
    __shared__ float2 Bbuf[NFFT*9];
    int t = threadIdx.x, c = t & 7, w = t >> 3;
    int ch = blockIdx.x / 36, cg = blockIdx.x % 36;
    float2* base = M + (size_t)ch * NFFT2 + cg*8 + c;
    float2* X = Abuf; float2* Y = Bbuf;
    for (int r = w; r < NFFT; r += 32) X[r*9 + c] = base[(size_t)r * NFFT];
    __syncthreads();
    fft288_s9<INV>(X, Y, w, c, tw);
    for (int r = w; r < NFFT; r += 32) base[(size_t)r * NFFT] = X[r*9 + c];
}

// ---------- forward row FFT fused with packed edge-pad load ----------
__global__ __launch_bounds__(256) void k_fft_rows_pad(const float* __restrict__ cls,
        float2* __restrict__ Z, const float2* __restrict__ tw) {
    __shared__ float2 A[4][NFFT];
    __shared__ float2 B[4][NFFT];
    int t = threadIdx.x, w = t >> 6, lane = t & 63;
    size_t row = (size_t)blockIdx.x*4 + w;
    int pc = (int)(row / NFFT), y = (int)(row % NFFT);
    int iy = min(max(y-21, 0), 245);
    const float* c0 = cls + (size_t)(2*pc)*NPIX + (size_t)iy*246;
    float2* X = A[w]; float2* Y = B[w];
    for (int j = lane; j < NFFT; j += 64) {
        int ix = min(max(j-21, 0), 245);
        X[j] = make_float2(c0[ix], c0[NPIX+ix]);
    }
    __syncthreads();
    fft288_row<false>(X, Y, lane, tw);
    float2* d = Z + row*NFFT;
    for (int j = lane; j < NFFT; j += 64) d[j] = X[j];
}

// ---------- FUSED: fwd col FFT + Wiener filter (analytic P, Hermitian in-block) + inv col FFT ----------
__global__ __launch_bounds__(256) void k_fft_cols_filter(float2* __restrict__ Z,
        const float2* __restrict__ KfT, const float* __restrict__ kP, const float2* __restrict__ tw) {
    __shared__ float2 Abuf[NFFT*9];
    __shared__ float2 Bbuf[NFFT*9];
    int t = threadIdx.x, c = t & 7, w = t >> 3;
    int ch = blockIdx.x / 36, g = blockIdx.x % 36;
    // column set: 4 pairs (x, 288-x); g==0 also holds the self-mirror cols 0 and 144
    int colc, pi;
    if (g == 0) {
        colc = (c < 4) ? c : (c == 4 ? 144 : 292 - c);
        pi   = (c == 0 || c == 4) ? c : (c < 4 ? c + 4 : c - 4);
    } else {
        colc = (c < 4) ? (4*g + c) : (288 - 4*g - (c - 4));
        pi   = c ^ 4;
    }
    float2* zb = Z + (size_t)ch * NFFT2 + colc;
    float2* X = Abuf; float2* Y = Bbuf;
    for (int r = w; r < NFFT; r += 32) X[r*9 + c] = zb[(size_t)r * NFFT];
    __syncthreads();
    fft288_s9<false>(X, Y, w, c, tw);
    // Wiener filter in LDS: point (y,colc) uses mirror (my, pair-col)
    {
        int b = ch >> 3;
        const float* pA = kP + (size_t)(2*ch)*9;
        const float* pB = pA + 9;
        float2 wx = tw[colc];
        const float2* Kcol = KfT + (size_t)b*NFFT2 + (size_t)colc*NFFT;
        for (int y = w; y < NFFT; y += 32) {
            int my = (y == 0) ? 0 : NFFT - y;
            float2 zk = X[y*9 + c];
            float2 zm = X[my*9 + pi];
            float2 K  = Kcol[y];
            float2 wy = tw[y];
            auto otf3 = [&](const float* p9) {
                float2 R0 = make_float2(p9[1] + (p9[0]+p9[2])*wx.x, (p9[2]-p9[0])*wx.y);
                float2 R1 = make_float2(p9[4] + (p9[3]+p9[5])*wx.x, (p9[5]-p9[3])*wx.y);
                float2 R2 = make_float2(p9[7] + (p9[6]+p9[8])*wx.x, (p9[8]-p9[6])*wx.y);
                float2 P;
                P.x = R1.x + wy.x*(R0.x+R2.x) - wy.y*(R2.y-R0.y);
                P.y = R1.y + wy.x*(R0.y+R2.y) + wy.y*(R2.x-R0.x);
                return P;
            };
            float2 Pa = otf3(pA);
            float2 Pb = otf3(pB);
            float2 A_ = make_float2(0.5f*(zk.x+zm.x),  0.5f*(zk.y-zm.y));
            float2 B_ = make_float2(0.5f*(zk.y+zm.y), -0.5f*(zk.x-zm.x));
            float kk = K.x*K.x + K.y*K.y;
            float ra = 1.0f / (kk + Pa.x*Pa.x + Pa.y*Pa.y);
            float rb = 1.0f / (kk + Pb.x*Pb.x + Pb.y*Pb.y);
            float2 Ha = make_float2(K.x*ra, -K.y*ra);
            float2 Hb = make_float2(K.x*rb, -K.y*rb);
            float2 Fa = cmul(Ha, A_);
            float2 Fb = cmul(Hb, B_);
            Y[y*9 + c] = make_float2(Fa.x - Fb.y, Fa.y + Fb.x);
        }
    }
    __syncthreads();
    { float2* tp = X; X = Y; Y = tp; }
    fft288_s9<true>(X, Y, w, c, tw);
    for (int r = w; r < NFFT; r += 32) zb[(size_t)r * NFFT] = X[r*9 + c];
}

// ---------- FUSED: inverse row FFT (8 ch-pairs per block) + crop + 1x1 conv 16->64 ----------
__global__ __launch_bounds__(256) void k_ifft_rows_conv(const float2* __restrict__ Z,
        const float* __restrict__ w_exp, const float* __restrict__ b_exp,
        float* __restrict__ out, const float2* __restrict__ tw) {
    __shared__ float2 Abuf[NFFT*9];
    __shared__ float2 Bbuf[NFFT*9];
    int t = threadIdx.x, c = t & 7, w = t >> 3;
    int b = blockIdx.x / 246;
    int rseq = blockIdx.x % 246;
    int y = rseq + 21;
    const float2* s = Z + (size_t)(b*8 + c) * NFFT2 + (size_t)y * NFFT;
    float2* X = Abuf; float2* Y = Bbuf;
    for (int j = w; j < NFFT; j += 32) X[j*9 + c] = s[j];
    __syncthreads();
    fft288_s9<true>(X, Y, w, c, tw);
    // conv 1x1 16->64 over this row, cropped to x in [21, 267)
    if (t < 246) {
        const float sc = 1.0f / 82944.0f;
        float v[16];
        #pragma unroll
        for (int h = 0; h < 8; h++) {
            float2 z = X[(t + 21)*9 + h];
            v[2*h]   = z.x * sc;
            v[2*h+1] = z.y * sc;
        }
        float* ob = out + (size_t)b * 64 * NPIX + (size_t)rseq * 246 + t;
        #pragma unroll
        for (int co = 0; co < 64; co++) {
            float a = b_exp[co];
            #pragma unroll
            for (int ci = 0; ci < 16; ci++) a = fmaf(w_exp[co*16+ci], v[ci], a);
            ob[(size_t)co * NPIX] = a;
        }
    }
}

extern "C" void kernel_launch(void* const* d_in, const int* in_sizes, int n_in,
                              void* d_out, int out_size, void* d_ws, size_t ws_size,
                              hipStream_t stream) {
    const float* x     = (const float*)d_in[0];
    const float* ker   = (const float*)d_in[1];
    const float* w_red = (const float*)d_in[2];
    const float* b_red = (const float*)d_in[3];
    const float* w_g1  = (const float*)d_in[4];
    const float* b_g1  = (const float*)d_in[5];
    const float* w_g2  = (const float*)d_in[6];
    const float* b_g2  = (const float*)d_in[7];
    const float* w_g3  = (const float*)d_in[8];
    const float* b_g3  = (const float*)d_in[9];
    const float* w_g4  = (const float*)d_in[10];
    const float* b_g4  = (const float*)d_in[11];
    const float* w_exp = (const float*)d_in[12];
    const float* b_exp = (const float*)d_in[13];
    float* out = (float*)d_out;

    char* ws = (char*)d_ws;
    size_t off = 0;
    auto alloc = [&](size_t bytes) -> char* {
        char* p = ws + off; off += (bytes + 255) & ~(size_t)255; return p;
    };
    float*  cls    = (float*) alloc(7746048ull * 4);            // (8,16,246,246)
    float2* Z      = (float2*)alloc((size_t)64 * NFFT2 * 8);    // packed spectrum / work
    float*  hb     = (float*) alloc(7495712ull * 4);            // (8,16,242,242) — DEDICATED (round-4 bug: aliasing this inside Z overflowed into KfT/tw)
    float2* KfT    = (float2*)alloc((size_t)8 * NFFT2 * 8);     // K spectrum transposed
    float*  pooled = (float*) alloc(1152 * 4);
    float*  kP     = (float*) alloc(1152 * 4);
    float2* tw     = (float2*)alloc(288 * 8);
    // ha aliases Z (7,620,608 floats <= 10,616,832 floats of Z; consumed before Z is written)
    float*  ha     = (float*)Z;

    k_tw<<<1, 320, 0, stream>>>(tw, pooled);
    k_conv1x1_red<<<1892, 256, 0, stream>>>(x, w_red, b_red, cls);
    k_conv3x3<246, true ><<<466, 256, 0, stream>>>(cls, w_g1, b_g1, ha);
    k_conv3x3<244, true ><<<462, 256, 0, stream>>>(ha,  w_g2, b_g2, hb);
    k_conv3x3_pool<<<456, 256, 0, stream>>>(hb, w_g3, b_g3, pooled);
    k_kernelP<<<128, 64, 0, stream>>>(pooled, w_g4, b_g4, kP);

    // KfT = fft2(psf(kernel)^T)  (rows then cols on transposed psf)
    k_psfKT<<<2592, 256, 0, stream>>>(ker, KfT);
    k_fft_rows<false><<<576, 256, 0, stream>>>(KfT, tw);
    k_fft_cols<false><<<288, 256, 0, stream>>>(KfT, tw);

    // Z = row-FFT(packed edge-pad(cls))
    k_fft_rows_pad<<<4608, 256, 0, stream>>>(cls, Z, tw);

    // fwd col FFT + Wiener + inv col FFT, all in LDS
    k_fft_cols_filter<<<2304, 256, 0, stream>>>(Z, KfT, kP, tw);

    // inverse row FFT + crop + final 1x1 conv
    k_ifft_rows_conv<<<1968, 256, 0, stream>>>(Z, w_exp, b_exp, out, tw);
}

// Round 6
// 342.580 us; speedup vs baseline: 2.2066x; 1.0441x over previous
//
#include <hip/hip_runtime.h>
#include <hip/hip_bf16.h>

// ---------- complex helpers ----------
__device__ inline float2 cadd(float2 a, float2 b){ return make_float2(a.x+b.x, a.y+b.y); }
__device__ inline float2 csub(float2 a, float2 b){ return make_float2(a.x-b.x, a.y-b.y); }
__device__ inline float2 cmul(float2 a, float2 b){
    return make_float2(fmaf(a.x,b.x,-a.y*b.y), fmaf(a.x,b.y,a.y*b.x));
}

#define NPIX 60516      // 246*246
#define NFFT 288
#define NFFT2 82944     // 288*288
#define XW 152          // padded half-spectrum width (valid x: 0..144)
#define SPLANE (NFFT*XW)

// LDS index for the 8-col layout: stride 8 + 1 pad float2 per 4 rows (38 KB/buffer-pair -> 4 blocks/CU)
__device__ inline int lidx(int i, int c){ return i*8 + (i>>2) + c; }
#define LDSN 2376

// ---------- butterflies ----------
template<bool INV>
__device__ inline void bf4(float2 a0, float2 a1, float2 a2, float2 a3,
                           float2& b0, float2& b1, float2& b2, float2& b3) {
    float2 t0=cadd(a0,a2), t1=csub(a0,a2), t2=cadd(a1,a3), t3=csub(a1,a3);
    b0=cadd(t0,t2); b2=csub(t0,t2);
    if (!INV) { b1=make_float2(t1.x+t3.y, t1.y-t3.x); b3=make_float2(t1.x-t3.y, t1.y+t3.x); }
    else      { b1=make_float2(t1.x-t3.y, t1.y+t3.x); b3=make_float2(t1.x+t3.y, t1.y-t3.x); }
}
template<bool INV>
__device__ inline void bf3(float2 a0, float2 a1, float2 a2,
                           float2& b0, float2& b1, float2& b2) {
    const float d = INV ? 0.8660254037844386f : -0.8660254037844386f;
    float2 tt=cadd(a1,a2), u=csub(a1,a2);
    b0=cadd(a0,tt);
    b1=make_float2(a0.x-0.5f*tt.x - d*u.y, a0.y-0.5f*tt.y + d*u.x);
    b2=make_float2(a0.x-0.5f*tt.x + d*u.y, a0.y-0.5f*tt.y - d*u.x);
}

// ---------- 288-pt Stockham core, contiguous layout (one wave per row) ----------
template<bool INV>
__device__ inline void fft288_row(float2*& X, float2*& Y, int lane, const float2* __restrict__ tw) {
    auto TW = [&](int k) { float2 v = tw[k]; if (INV) v.y = -v.y; return v; };
    for (int p = lane; p < 72; p += 64) {
        float2 b0,b1,b2,b3;
        bf4<INV>(X[p], X[p+72], X[p+144], X[p+216], b0,b1,b2,b3);
        Y[4*p]=b0; Y[4*p+1]=cmul(b1,TW(p)); Y[4*p+2]=cmul(b2,TW(2*p)); Y[4*p+3]=cmul(b3,TW(3*p));
    }
    __syncthreads(); { float2* t=X; X=Y; Y=t; }
    for (int it = lane; it < 72; it += 64) {
        int p = it>>2, q = it&3, i0 = q+4*p;
        float2 b0,b1,b2,b3;
        bf4<INV>(X[i0], X[i0+72], X[i0+144], X[i0+216], b0,b1,b2,b3);
        int o = q+16*p;
        Y[o]=b0; Y[o+4]=cmul(b1,TW(4*p)); Y[o+8]=cmul(b2,TW(8*p)); Y[o+12]=cmul(b3,TW(12*p));
    }
    __syncthreads(); { float2* t=X; X=Y; Y=t; }
    for (int it = lane; it < 144; it += 64) {
        int p = it>>4, q = it&15, i0 = q+16*p;
        float2 a0=X[i0], a1=X[i0+144];
        int o = q+32*p;
        Y[o]=cadd(a0,a1); Y[o+16]=cmul(csub(a0,a1),TW(16*p));
    }
    __syncthreads(); { float2* t=X; X=Y; Y=t; }
    for (int it = lane; it < 96; it += 64) {
        int p = it>>5, q = it&31, i0 = q+32*p;
        float2 b0,b1,b2;
        bf3<INV>(X[i0], X[i0+96], X[i0+192], b0,b1,b2);
        int o = q+96*p;
        Y[o]=b0; Y[o+32]=cmul(b1,TW(32*p)); Y[o+64]=cmul(b2,TW(64*p));
    }
    __syncthreads(); { float2* t=X; X=Y; Y=t; }
    for (int q = lane; q < 96; q += 64) {
        float2 b0,b1,b2;
        bf3<INV>(X[q], X[q+96], X[q+192], b0,b1,b2);
        Y[q]=b0; Y[q+96]=b1; Y[q+192]=b2;
    }
    __syncthreads(); { float2* t=X; X=Y; Y=t; }
}

// ---------- 288-pt Stockham core, lidx layout (8 lanes share, 32 row-slots) ----------
template<bool INV>
__device__ inline void fft288_s9(float2*& X, float2*& Y, int w, int c, const float2* __restrict__ tw) {
    auto TW = [&](int k) { float2 v = tw[k]; if (INV) v.y = -v.y; return v; };
    for (int p = w; p < 72; p += 32) {
        float2 b0,b1,b2,b3;
        bf4<INV>(X[lidx(p,c)], X[lidx(p+72,c)], X[lidx(p+144,c)], X[lidx(p+216,c)], b0,b1,b2,b3);
        Y[lidx(4*p,c)]=b0; Y[lidx(4*p+1,c)]=cmul(b1,TW(p));
        Y[lidx(4*p+2,c)]=cmul(b2,TW(2*p)); Y[lidx(4*p+3,c)]=cmul(b3,TW(3*p));
    }
    __syncthreads(); { float2* t=X; X=Y; Y=t; }
    for (int it = w; it < 72; it += 32) {
        int p = it>>2, q = it&3, i0 = q+4*p;
        float2 b0,b1,b2,b3;
        bf4<INV>(X[lidx(i0,c)], X[lidx(i0+72,c)], X[lidx(i0+144,c)], X[lidx(i0+216,c)], b0,b1,b2,b3);
        int o = q+16*p;
        Y[lidx(o,c)]=b0; Y[lidx(o+4,c)]=cmul(b1,TW(4*p));
        Y[lidx(o+8,c)]=cmul(b2,TW(8*p)); Y[lidx(o+12,c)]=cmul(b3,TW(12*p));
    }
    __syncthreads(); { float2* t=X; X=Y; Y=t; }
    for (int it = w; it < 144; it += 32) {
        int p = it>>4, q = it&15, i0 = q+16*p;
        float2 a0=X[lidx(i0,c)], a1=X[lidx(i0+144,c)];
        int o = q+32*p;
        Y[lidx(o,c)]=cadd(a0,a1); Y[lidx(o+16,c)]=cmul(csub(a0,a1),TW(16*p));
    }
    __syncthreads(); { float2* t=X; X=Y; Y=t; }
    for (int it = w; it < 96; it += 32) {
        int p = it>>5, q = it&31, i0 = q+32*p;
        float2 b0,b1,b2;
        bf3<INV>(X[lidx(i0,c)], X[lidx(i0+96,c)], X[lidx(i0+192,c)], b0,b1,b2);
        int o = q+96*p;
        Y[lidx(o,c)]=b0; Y[lidx(o+32,c)]=cmul(b1,TW(32*p)); Y[lidx(o+64,c)]=cmul(b2,TW(64*p));
    }
    __syncthreads(); { float2* t=X; X=Y; Y=t; }
    for (int q = w; q < 96; q += 32) {
        float2 b0,b1,b2;
        bf3<INV>(X[lidx(q,c)], X[lidx(q+96,c)], X[lidx(q+192,c)], b0,b1,b2);
        Y[lidx(q,c)]=b0; Y[lidx(q+96,c)]=b1; Y[lidx(q+192,c)]=b2;
    }
    __syncthreads(); { float2* t=X; X=Y; Y=t; }
}

// ---------- prep: twiddles + zero pooled ----------
__global__ void k_tw(float2* tw, float* pooled) {
    int t = threadIdx.x;
    if (t < NFFT) {
        double ang = -2.0 * 3.14159265358979323846 * (double)t / (double)NFFT;
        tw[t] = make_float2((float)cos(ang), (float)sin(ang));
    }
    for (int i = t; i < 1152; i += 320) pooled[i] = 0.f;
}

// ---------- 1x1 conv 64->16 ----------
__global__ __launch_bounds__(256) void k_conv1x1_red(const float* __restrict__ x,
        const float* __restrict__ w, const float* __restrict__ bias, float* __restrict__ out) {
    int idx = blockIdx.x * 256 + threadIdx.x;
    if (idx >= 8 * NPIX) return;
    int b = idx / NPIX, p = idx % NPIX;
    const float* xb = x + (size_t)b * 64 * NPIX + p;
    float acc[16];
    #pragma unroll
    for (int co = 0; co < 16; co++) acc[co] = bias[co];
    for (int ci = 0; ci < 64; ci++) {
        float v = xb[(size_t)ci * NPIX];
        #pragma unroll
        for (int co = 0; co < 16; co++) acc[co] = fmaf(w[co*64+ci], v, acc[co]);
    }
    float* ob = out + (size_t)b * 16 * NPIX + p;
    #pragma unroll
    for (int co = 0; co < 16; co++) ob[(size_t)co*NPIX] = acc[co];
}

// ---------- 3x3 valid conv 16->16, 4 px/thread, scalar weights ----------
template<int HIN, bool LEAKY>
__global__ __launch_bounds__(256) void k_conv3x3(const float* __restrict__ in,
        const float* __restrict__ w, const float* __restrict__ bias, float* __restrict__ out) {
    const int HOUT = HIN - 2;
    const int GX = (HOUT + 3) / 4;
    int idx = blockIdx.x * 256 + threadIdx.x;
    if (idx >= 8 * HOUT * GX) return;
    int b  = idx / (HOUT * GX);
    int r  = idx % (HOUT * GX);
    int oy = r / GX;
    int ox0 = (r % GX) * 4;

    float acc[16][4];
    #pragma unroll
    for (int co = 0; co < 16; co++) {
        float bb = bias[co];
        #pragma unroll
        for (int px = 0; px < 4; px++) acc[co][px] = bb;
    }
    const float* ib = in + (size_t)b * 16 * HIN * HIN + (size_t)oy * HIN;
    for (int ci = 0; ci < 16; ci++) {
        const float* ic = ib + (size_t)ci * HIN * HIN;
        #pragma unroll
        for (int ky = 0; ky < 3; ky++) {
            float in6[6];
            #pragma unroll
            for (int j = 0; j < 6; j++) {
                int xx = ox0 + j;
                if (HOUT % 4 != 0) { if (xx > HIN - 1) xx = HIN - 1; }
                in6[j] = ic[ky * HIN + xx];
            }
            #pragma unroll
            for (int kx = 0; kx < 3; kx++) {
                #pragma unroll
                for (int co = 0; co < 16; co++) {
                    float wv = w[co*144 + ci*9 + ky*3 + kx];
                    #pragma unroll
                    for (int px = 0; px < 4; px++)
                        acc[co][px] = fmaf(wv, in6[px + kx], acc[co][px]);
                }
            }
        }
    }
    float* ob = out + (size_t)b * 16 * HOUT * HOUT + (size_t)oy * HOUT + ox0;
    #pragma unroll
    for (int co = 0; co < 16; co++) {
        #pragma unroll
        for (int px = 0; px < 4; px++) {
            if (HOUT % 4 == 0 || ox0 + px < HOUT) {
                float v = acc[co][px];
                if (LEAKY) v = (v >= 0.f) ? v : 0.1f * v;
                ob[(size_t)co * HOUT * HOUT + px] = v;
            }
        }
    }
}

// ---------- 3x3 conv (242->240) fused with adaptive pool -> pooled (raw sums) ----------
__global__ __launch_bounds__(256) void k_conv3x3_pool(const float* __restrict__ in,
        const float* __restrict__ w, const float* __restrict__ bias, float* __restrict__ pooled) {
    const int HIN = 242, GX = 60;
    __shared__ float cs[144];
    int t = threadIdx.x;
    int b = blockIdx.x / 57;
    int r = (blockIdx.x % 57) * 256 + t;
    bool valid = r < 14400;
    float partial[16];
    int cell = 0;
    if (valid) {
        int oy = r / GX, ox0 = (r % GX) * 4;
        cell = (oy / 80) * 3 + (ox0 / 80);
        float acc[16][4];
        #pragma unroll
        for (int co = 0; co < 16; co++) {
            float bb = bias[co];
            #pragma unroll
            for (int px = 0; px < 4; px++) acc[co][px] = bb;
        }
        const float* ib = in + (size_t)b * 16 * HIN * HIN + (size_t)oy * HIN;
        for (int ci = 0; ci < 16; ci++) {
            const float* ic = ib + (size_t)ci * HIN * HIN;
            #pragma unroll
            for (int ky = 0; ky < 3; ky++) {
                float in6[6];
                #pragma unroll
                for (int j = 0; j < 6; j++) in6[j] = ic[ky * HIN + ox0 + j];
                #pragma unroll
                for (int kx = 0; kx < 3; kx++) {
                    #pragma unroll
                    for (int co = 0; co < 16; co++) {
                        float wv = w[co*144 + ci*9 + ky*3 + kx];
                        #pragma unroll
                        for (int px = 0; px < 4; px++)
                            acc[co][px] = fmaf(wv, in6[px + kx], acc[co][px]);
                    }
                }
            }
        }
        #pragma unroll
        for (int co = 0; co < 16; co++)
            partial[co] = (acc[co][0] + acc[co][1]) + (acc[co][2] + acc[co][3]);
    }
    if (t < 144) cs[t] = 0.f;
    __syncthreads();
    if (valid) {
        #pragma unroll
        for (int co = 0; co < 16; co++) atomicAdd(&cs[co*9 + cell], partial[co]);
    }
    __syncthreads();
    if (t < 144) atomicAdd(&pooled[b*144 + t], cs[t]);
}

// ---------- kernel_P: 1x1 conv (16->16) + exp + spatial-mean subtraction ----------
__global__ void k_kernelP(const float* __restrict__ pooled, const float* __restrict__ w,
                          const float* __restrict__ bias, float* __restrict__ out) {
    int b = blockIdx.x / 16, co = blockIdx.x % 16;
    __shared__ float vals[9];
    int t = threadIdx.x;
    if (t < 9) {
        float a = 0.f;
        for (int ci = 0; ci < 16; ci++) a += pooled[(b*16+ci)*9 + t] * w[co*16+ci];
        vals[t] = expf(bias[co] + a * (1.f/6400.f));
    }
    __syncthreads();
    if (t < 9) {
        float m = 0.f;
        #pragma unroll
        for (int i = 0; i < 9; i++) m += vals[i];
        m *= (1.f/9.f);
        out[(b*16+co)*9 + t] = vals[t] - m;
    }
}

// ---------- psf builder for K, TRANSPOSED: KfT[b][u][v] = psf[b][v][u] ----------
__global__ __launch_bounds__(256) void k_psfKT(const float* __restrict__ ker, float2* __restrict__ KfT) {
    int idx = blockIdx.x*256 + threadIdx.x;
    if (idx >= 8*NFFT2) return;
    int pos = idx % NFFT2, b = idx / NFFT2;
    int u = pos / NFFT, v = pos % NFFT;
    int ry = (v < 11) ? v+10 : ((v >= 278) ? v-278 : -1);
    int rx = (u < 11) ? u+10 : ((u >= 278) ? u-278 : -1);
    float val = (ry >= 0 && rx >= 0) ? ker[b*441 + ry*21 + rx] : 0.f;
    KfT[idx] = make_float2(val, 0.f);
}

// ---------- plain row FFT (for KfT) ----------
template<bool INV>
__global__ __launch_bounds__(256) void k_fft_rows(float2* __restrict__ M, const float2* __restrict__ tw) {
    __shared__ float2 A[4][NFFT];
    __shared__ float2 B[4][NFFT];
    int t = threadIdx.x, w = t >> 6, lane = t & 63;
    size_t row = (size_t)blockIdx.x*4 + w;
    float2* X = A[w]; float2* Y = B[w];
    float2* s = M + row*NFFT;
    for (int j = lane; j < NFFT; j += 64) X[j] = s[j];
    __syncthreads();
    fft288_row<INV>(X, Y, lane, tw);
    for (int j = lane; j < NFFT; j += 64) s[j] = X[j];
}

// ---------- plain col FFT (for KfT) ----------
template<bool INV>
__global__ __launch_bounds__(256) void k_fft_cols(float2* __restrict__ M, const float2* __restrict__ tw) {
    __shared__ float2 Abuf[LDSN];
    __shared__ float2 Bbuf[LDSN];
    int t = threadIdx.x, c = t & 7, w = t >> 3;
    int ch = blockIdx.x / 36, cg = blockIdx.x % 36;
    float2* base = M + (size_t)ch * NFFT2 + cg*8 + c;
    float2* X = Abuf; float2* Y = Bbuf;
    for (int r = w; r < NFFT; r += 32) X[lidx(r,c)] = base[(size_t)r * NFFT];
    __syncthreads();
    fft288_s9<INV>(X, Y, w, c, tw);
    for (int r = w; r < NFFT; r += 32) base[(size_t)r * NFFT] = X[lidx(r,c)];
}

// ---------- forward row FFT + edge-pad + per-row real unpack -> half spectra S ----------
__global__ __launch_bounds__(256) void k_fft_rows_pad_half(const float* __restrict__ cls,
        float2* __restrict__ S, const float2* __restrict__ tw) {
    __shared__ float2 A[4][NFFT];
    __shared__ float2 B[4][NFFT];
    int t = threadIdx.x, w = t >> 6, lane = t & 63;
    size_t row = (size_t)blockIdx.x*4 + w;
    int pc = (int)(row / NFFT), y = (int)(row % NFFT);
    int iy = min(max(y-21, 0), 245);
    const float* c0 = cls + (size_t)(2*pc)*NPIX + (size_t)iy*246;
    float2* X = A[w]; float2* Y = B[w];
    for (int j = lane; j < NFFT; j += 64) {
        int ix = min(max(j-21, 0), 245);
        X[j] = make_float2(c0[ix], c0[NPIX+ix]);
    }
    __syncthreads();
    fft288_row<false>(X, Y, lane, tw);
    // unpack two real spectra (row-mirror within this row), store half width
    int chA = (pc >> 3)*16 + (pc & 7)*2;
    float2* sA = S + (size_t)chA * SPLANE + (size_t)y * XW;
    float2* sB = sA + SPLANE;
    for (int x = lane; x < XW; x += 64) {
        float2 Av = make_float2(0.f, 0.f), Bv = make_float2(0.f, 0.f);
        if (x <= 144) {
            int m = (NFFT - x) % NFFT;
            float2 zk = X[x], zm = X[m];
            Av = make_float2(0.5f*(zk.x+zm.x),  0.5f*(zk.y-zm.y));
            Bv = make_float2(0.5f*(zk.y+zm.y), -0.5f*(zk.x-zm.x));
        }
        sA[x] = Av; sB[x] = Bv;
    }
}

// ---------- FUSED: fwd col FFT + pointwise Wiener (analytic P, no mirror) + inv col FFT ----------
__global__ __launch_bounds__(256) void k_fft_cols_filter(float2* __restrict__ S,
        const float2* __restrict__ KfT, const float* __restrict__ kP, const float2* __restrict__ tw) {
    __shared__ float2 Abuf[LDSN];
    __shared__ float2 Bbuf[LDSN];
    int t = threadIdx.x, c = t & 7, w = t >> 3;
    int g = blockIdx.x / 128, ch = blockIdx.x % 128;   // g-major: K columns L2-resident
    int xg = g*8 + c;                                   // 0..151
    int b = ch >> 4;
    float2* sb = S + (size_t)ch * SPLANE + xg;
    float2* X = Abuf; float2* Y = Bbuf;
    for (int r = w; r < NFFT; r += 32) X[lidx(r,c)] = sb[(size_t)r * XW];
    __syncthreads();
    fft288_s9<false>(X, Y, w, c, tw);
    // pointwise Wiener: F(ky,xg) = conj(K)/(|K|^2+|P|^2) * Ahat
    {
        const float* p9 = kP + ch*9;                    // block-uniform -> SGPR
        float2 wx = tw[xg];
        const float2* Kcol = KfT + (size_t)b*NFFT2 + (size_t)xg*NFFT;
        for (int y = w; y < NFFT; y += 32) {
            float2 v = X[lidx(y,c)];
            float2 K = Kcol[y];
            float2 wy = tw[y];
            float2 R0 = make_float2(p9[1] + (p9[0]+p9[2])*wx.x, (p9[2]-p9[0])*wx.y);
            float2 R1 = make_float2(p9[4] + (p9[3]+p9[5])*wx.x, (p9[5]-p9[3])*wx.y);
            float2 R2 = make_float2(p9[7] + (p9[6]+p9[8])*wx.x, (p9[8]-p9[6])*wx.y);
            float2 P;
            P.x = R1.x + wy.x*(R0.x+R2.x) - wy.y*(R2.y-R0.y);
            P.y = R1.y + wy.x*(R0.y+R2.y) + wy.y*(R2.x-R0.x);
            float kk = K.x*K.x + K.y*K.y;
            float rcp = 1.0f / (kk + P.x*P.x + P.y*P.y);
            float2 H = make_float2(K.x*rcp, -K.y*rcp);
            Y[lidx(y,c)] = cmul(H, v);
        }
    }
    __syncthreads();
    { float2* tp = X; X = Y; Y = tp; }
    fft288_s9<true>(X, Y, w, c, tw);
    // write back only rows needed by the crop [21,267)
    for (int r = w; r < NFFT; r += 32)
        if (r >= 21 && r < 267) sb[(size_t)r * XW] = X[lidx(r,c)];
}

// ---------- FUSED: repack half spectra + inverse row FFT + crop + 1x1 conv 16->64 ----------
__global__ __launch_bounds__(256) void k_ifft_rows_conv(const float2* __restrict__ S,
        const float* __restrict__ w_exp, const float* __restrict__ b_exp,
        float* __restrict__ out, const float2* __restrict__ tw) {
    __shared__ float2 Abuf[LDSN];
    __shared__ float2 Bbuf[LDSN];
    int t = threadIdx.x, c = t & 7, w = t >> 3;
    int b = blockIdx.x / 246;
    int rseq = blockIdx.x % 246;
    int y = rseq + 21;
    int chA = b*16 + 2*c;
    const float2* sA = S + (size_t)chA * SPLANE + (size_t)y * XW;
    const float2* sB = sA + SPLANE;
    float2* X = Abuf; float2* Y = Bbuf;
    for (int j = w; j < NFFT; j += 32) {
        float2 z;
        if (j <= 144) {
            float2 a = sA[j], bb = sB[j];
            z = make_float2(a.x - bb.y, a.y + bb.x);          // Fa + i*Fb
        } else {
            int m = NFFT - j;
            float2 a = sA[m], bb = sB[m];
            z = make_float2(a.x + bb.y, bb.x - a.y);          // conj(Fa) + i*conj(Fb)
        }
        X[lidx(j,c)] = z;
    }
    __syncthreads();
    fft288_s9<true>(X, Y, w, c, tw);
    if (t < 246) {
        const float sc = 1.0f / 82944.0f;
        float v[16];
        #pragma unroll
        for (int h = 0; h < 8; h++) {
            float2 z = X[lidx(t + 21, h)];
            v[2*h]   = z.x * sc;
            v[2*h+1] = z.y * sc;
        }
        float* ob = out + (size_t)b * 64 * NPIX + (size_t)rseq * 246 + t;
        #pragma unroll
        for (int co = 0; co < 64; co++) {
            float a = b_exp[co];
            #pragma unroll
            for (int ci = 0; ci < 16; ci++) a = fmaf(w_exp[co*16+ci], v[ci], a);
            ob[(size_t)co * NPIX] = a;
        }
    }
}

extern "C" void kernel_launch(void* const* d_in, const int* in_sizes, int n_in,
                              void* d_out, int out_size, void* d_ws, size_t ws_size,
                              hipStream_t stream) {
    const float* x     = (const float*)d_in[0];
    const float* ker   = (const float*)d_in[1];
    const float* w_red = (const float*)d_in[2];
    const float* b_red = (const float*)d_in[3];
    const float* w_g1  = (const float*)d_in[4];
    const float* b_g1  = (const float*)d_in[5];
    const float* w_g2  = (const float*)d_in[6];
    const float* b_g2  = (const float*)d_in[7];
    const float* w_g3  = (const float*)d_in[8];
    const float* b_g3  = (const float*)d_in[9];
    const float* w_g4  = (const float*)d_in[10];
    const float* b_g4  = (const float*)d_in[11];
    const float* w_exp = (const float*)d_in[12];
    const float* b_exp = (const float*)d_in[13];
    float* out = (float*)d_out;

    char* ws = (char*)d_ws;
    size_t off = 0;
    auto alloc = [&](size_t bytes) -> char* {
        char* p = ws + off; off += (bytes + 255) & ~(size_t)255; return p;
    };
    float*  cls    = (float*) alloc(7746048ull * 4);              // (8,16,246,246)
    float2* S      = (float2*)alloc((size_t)128 * SPLANE * 8);    // half spectra (128,288,152)
    float*  hb     = (float*) alloc(7495712ull * 4);              // (8,16,242,242) dedicated
    float2* KfT    = (float2*)alloc((size_t)8 * NFFT2 * 8);       // K spectrum transposed
    float*  pooled = (float*) alloc(1152 * 4);
    float*  kP     = (float*) alloc(1152 * 4);
    float2* tw     = (float2*)alloc(288 * 8);
    // ha aliases S (needs 7,620,608 floats <= 11,206,656 float2 of S; dead before S written)
    float*  ha     = (float*)S;

    k_tw<<<1, 320, 0, stream>>>(tw, pooled);
    k_conv1x1_red<<<1892, 256, 0, stream>>>(x, w_red, b_red, cls);
    k_conv3x3<246, true ><<<466, 256, 0, stream>>>(cls, w_g1, b_g1, ha);
    k_conv3x3<244, true ><<<462, 256, 0, stream>>>(ha,  w_g2, b_g2, hb);
    k_conv3x3_pool<<<456, 256, 0, stream>>>(hb, w_g3, b_g3, pooled);
    k_kernelP<<<128, 64, 0, stream>>>(pooled, w_g4, b_g4, kP);

    // KfT = fft2(psf(kernel)^T)
    k_psfKT<<<2592, 256, 0, stream>>>(ker, KfT);
    k_fft_rows<false><<<576, 256, 0, stream>>>(KfT, tw);
    k_fft_cols<false><<<288, 256, 0, stream>>>(KfT, tw);

    // S = per-row-unpacked half spectra of edge-padded cls (packed row FFT)
    k_fft_rows_pad_half<<<4608, 256, 0, stream>>>(cls, S, tw);

    // fwd col FFT + pointwise Wiener + inv col FFT, in LDS (19 col-groups x 128 ch)
    k_fft_cols_filter<<<19*128, 256, 0, stream>>>(S, KfT, kP, tw);

    // repack + inverse row FFT + crop + final 1x1 conv
    k_ifft_rows_conv<<<1968, 256, 0, stream>>>(S, w_exp, b_exp, out, tw);
}